// Round 2
// baseline (19828.935 us; speedup 1.0000x reference)
//
#include <hip/hip_runtime.h>
#include <hip/hip_bf16.h>
#include <stdint.h>

typedef unsigned short u16;
typedef unsigned int u32;
typedef __attribute__((ext_vector_type(8))) short s16x8;
typedef __attribute__((ext_vector_type(4))) float f32x4;

static __device__ __forceinline__ float bf2f(u16 u){
  unsigned v = ((unsigned)u) << 16; return __builtin_bit_cast(float, v);
}
static __device__ __forceinline__ u16 f2bf(float f){
  unsigned u = __builtin_bit_cast(unsigned, f);
  u += 0x7FFFu + ((u >> 16) & 1u);
  return (u16)(u >> 16);
}
static __device__ __forceinline__ float sigm(float x){ return 1.f / (1.f + __expf(-x)); }

typedef __attribute__((address_space(1))) const u32 gu32;
typedef __attribute__((address_space(3))) u32 lu32;
static __device__ __forceinline__ void gload_lds16(const void* g, void* l){
  __builtin_amdgcn_global_load_lds((gu32*)g, (lu32*)l, 16, 0, 0);
}

// SYNC layout (u32 idx): leaf[g]=SYNC[g*32] g<32; ROOT=1024; REL=1056; OUTFLAG=1088; READY=1120+b
#define SY_ROOT 1024
#define SY_REL  1056
#define SY_OFLG 1088
#define SY_RDY  1120

// ---------------- prep kernels ----------------

__global__ __launch_bounds__(256) void k_wfull(const float* __restrict__ wih,
                                               const float* __restrict__ whh,
                                               u16* __restrict__ wf){
  int stride = gridDim.x * blockDim.x;
  for (int i = blockIdx.x * blockDim.x + threadIdx.x; i < 2048 * 1280; i += stride){
    int j = i / 1280, k = i - j * 1280;
    float v = (k < 768) ? wih[j * 768 + k] : whh[j * 512 + (k - 768)];
    wf[i] = f2bf(v);
  }
}

__global__ __launch_bounds__(256) void k_whmt(const float* __restrict__ whm,
                                              u16* __restrict__ wt){
  int stride = gridDim.x * blockDim.x;
  for (int i = blockIdx.x * blockDim.x + threadIdx.x; i < 512 * 512; i += stride){
    int n = i >> 9, k = i & 511;
    wt[i] = f2bf(whm[k * 512 + n]);
  }
}

__global__ __launch_bounds__(256) void k_cvt(const float* __restrict__ s,
                                             u16* __restrict__ d, int n){
  int stride = gridDim.x * blockDim.x * 4;
  for (int i = (blockIdx.x * blockDim.x + threadIdx.x) * 4; i < n; i += stride){
    float4 v = *(const float4*)&s[i];
    d[i + 0] = f2bf(v.x); d[i + 1] = f2bf(v.y);
    d[i + 2] = f2bf(v.z); d[i + 3] = f2bf(v.w);
  }
}

__global__ __launch_bounds__(256) void k_xs(const int* __restrict__ seq,
                                            const float* __restrict__ emb,
                                            u16* __restrict__ xs){
  int stride = gridDim.x * blockDim.x;
  for (int i = blockIdx.x * blockDim.x + threadIdx.x; i < 8192 * 256; i += stride){
    int m = i >> 8, e = i & 255;
    float v = emb[(size_t)seq[m] * 256 + e];
    xs[i] = f2bf(v > 0.f ? v : 0.f);
  }
}

// ---------------- 128x128 bf16 MFMA GEMM: C = A[M,K] @ B[N,K]^T ----------------

template<int OUTBF, int HASBIAS, int NG>
__global__ __launch_bounds__(256) void k_gemm(const u16* __restrict__ A,
                                              const u16* __restrict__ Bm,
                                              void* __restrict__ Cout,
                                              const float* __restrict__ bias,
                                              int M, int N, int K){
  __shared__ __align__(16) u16 As[128 * 64];
  __shared__ __align__(16) u16 Bs[128 * 64];
  int tid = threadIdx.x; int w = tid >> 6; int l = tid & 63;
  int m0 = blockIdx.x * 128, n0 = blockIdx.y * 128;
  int wr = w >> 1, wc = w & 1;
  f32x4 acc[4][4];
#pragma unroll
  for (int a = 0; a < 4; a++)
#pragma unroll
    for (int b = 0; b < 4; b++){ f32x4 z = {0.f,0.f,0.f,0.f}; acc[a][b] = z; }
  int rA = m0 + (tid >> 3);
  int rB = n0 + (tid >> 3);
  for (int k0 = 0; k0 < K; k0 += 64){
    __syncthreads();
    int ca = k0 + (tid & 7) * 8;
#pragma unroll
    for (int i = 0; i < 4; i++){
      gload_lds16(&A[(size_t)(rA + i * 32) * K + ca], &As[i * 2048 + w * 512]);
      int rb = rB + i * 32;
      if (NG) rb = (rb < N - 1) ? rb : (N - 1);
      gload_lds16(&Bm[(size_t)rb * K + ca], &Bs[i * 2048 + w * 512]);
    }
    asm volatile("s_waitcnt vmcnt(0)" ::: "memory");
    __syncthreads();
#pragma unroll
    for (int ks = 0; ks < 2; ks++){
      s16x8 av[4], bv[4];
      int ko = ks * 32 + (l >> 4) * 8;
#pragma unroll
      for (int i = 0; i < 4; i++) av[i] = *(const s16x8*)&As[(wr * 64 + i * 16 + (l & 15)) * 64 + ko];
#pragma unroll
      for (int i = 0; i < 4; i++) bv[i] = *(const s16x8*)&Bs[(wc * 64 + i * 16 + (l & 15)) * 64 + ko];
#pragma unroll
      for (int mi = 0; mi < 4; mi++)
#pragma unroll
        for (int ni = 0; ni < 4; ni++)
          acc[mi][ni] = __builtin_amdgcn_mfma_f32_16x16x32_bf16(av[mi], bv[ni], acc[mi][ni], 0, 0, 0);
    }
  }
#pragma unroll
  for (int mi = 0; mi < 4; mi++)
#pragma unroll
    for (int ni = 0; ni < 4; ni++){
      int row = m0 + wr * 64 + mi * 16 + (l >> 4) * 4;
      int col = n0 + wc * 64 + ni * 16 + (l & 15);
      if (NG && col >= N) continue;
#pragma unroll
      for (int r = 0; r < 4; r++){
        float v = acc[mi][ni][r];
        if (HASBIAS) v += bias[col];
        if (OUTBF) ((u16*)Cout)[(size_t)(row + r) * N + col] = f2bf(v);
        else       ((float*)Cout)[(size_t)(row + r) * N + col] = v;
      }
    }
}

// ---------------- grid barrier (tree: 32 leaves x 8, then root) ----------------

static __device__ __forceinline__ void gbar(u32* SYNC, int gid, u32 ph){
  __syncthreads();
  if (threadIdx.x == 0){
    __threadfence();
    u32 p = atomicAdd(&SYNC[(gid >> 3) << 5], 1u);
    if ((p & 7u) == 7u){
      u32 q = atomicAdd(&SYNC[SY_ROOT], 1u);
      if (q == ph * 32u + 31u)
        __hip_atomic_store(&SYNC[SY_REL], ph + 1u, __ATOMIC_RELEASE, __HIP_MEMORY_SCOPE_AGENT);
    }
    while (__hip_atomic_load(&SYNC[SY_REL], __ATOMIC_RELAXED, __HIP_MEMORY_SCOPE_AGENT) <= ph)
      __builtin_amdgcn_s_sleep(2);
    __threadfence();
  }
  __syncthreads();
}

// ---------------- phase: gates + LSTM for step tn (32 wgs, gid<32) ----------------
// gates(tn) = [x(tn) | out(tn-1) | h(tn-1)] @ WF^T. x,h segments first; spin for
// out-flag (out(tn-1) complete), then out segment. 4-wave K-split, LDS-reduce.

static __device__ void gates_phase(const u16* __restrict__ WF, const u16* __restrict__ XS,
                                   u16* __restrict__ Z, float* __restrict__ CST,
                                   u32* __restrict__ SYNC, float* __restrict__ SM,
                                   int gid, int tn, int first){
  int tid = threadIdx.x, w = tid >> 6, l = tid & 63;
  int ns = gid << 4;
  float (*red)[32][64] = (float(*)[32][64])SM;
  f32x4 acc[2][4];
#pragma unroll
  for (int a = 0; a < 2; a++)
#pragma unroll
    for (int b = 0; b < 4; b++){ f32x4 z = {0.f,0.f,0.f,0.f}; acc[a][b] = z; }

  // x segment: K [0,256), per-wave 64
  for (int k = w * 64; k < w * 64 + 64; k += 32){
    int ko = k + (l >> 4) * 8;
    s16x8 av[2], bv[4];
#pragma unroll
    for (int mi = 0; mi < 2; mi++){
      int bi = mi * 16 + (l & 15);
      av[mi] = *(const s16x8*)&XS[(size_t)(bi * 256 + tn) * 256 + ko];
    }
#pragma unroll
    for (int gi = 0; gi < 4; gi++)
      bv[gi] = *(const s16x8*)&WF[(size_t)(gi * 512 + ns + (l & 15)) * 1280 + ko];
#pragma unroll
    for (int mi = 0; mi < 2; mi++)
#pragma unroll
      for (int gi = 0; gi < 4; gi++)
        acc[mi][gi] = __builtin_amdgcn_mfma_f32_16x16x32_bf16(av[mi], bv[gi], acc[mi][gi], 0, 0, 0);
  }
  if (!first){
    // h segment: K [768,1280), per-wave 128  (Z offset = k - 256 -> h half)
    for (int k = 768 + w * 128; k < 768 + w * 128 + 128; k += 32){
      int ko = k + (l >> 4) * 8;
      s16x8 av[2], bv[4];
#pragma unroll
      for (int mi = 0; mi < 2; mi++){
        int bi = mi * 16 + (l & 15);
        av[mi] = *(const s16x8*)&Z[(size_t)bi * 1024 + (ko - 256)];
      }
#pragma unroll
      for (int gi = 0; gi < 4; gi++)
        bv[gi] = *(const s16x8*)&WF[(size_t)(gi * 512 + ns + (l & 15)) * 1280 + ko];
#pragma unroll
      for (int mi = 0; mi < 2; mi++)
#pragma unroll
        for (int gi = 0; gi < 4; gi++)
          acc[mi][gi] = __builtin_amdgcn_mfma_f32_16x16x32_bf16(av[mi], bv[gi], acc[mi][gi], 0, 0, 0);
    }
    // wait until out(tn-1) is complete: OUTFLAG >= 16*tn
    if (tid == 0){
      while (__hip_atomic_load(&SYNC[SY_OFLG], __ATOMIC_RELAXED, __HIP_MEMORY_SCOPE_AGENT) < 16u * (u32)tn)
        __builtin_amdgcn_s_sleep(2);
      __threadfence();
    }
    __syncthreads();
    // out segment: K [256,768), per-wave 128
    for (int k = 256 + w * 128; k < 256 + w * 128 + 128; k += 32){
      int ko = k + (l >> 4) * 8;
      s16x8 av[2], bv[4];
#pragma unroll
      for (int mi = 0; mi < 2; mi++){
        int bi = mi * 16 + (l & 15);
        av[mi] = *(const s16x8*)&Z[(size_t)bi * 1024 + (ko - 256)];
      }
#pragma unroll
      for (int gi = 0; gi < 4; gi++)
        bv[gi] = *(const s16x8*)&WF[(size_t)(gi * 512 + ns + (l & 15)) * 1280 + ko];
#pragma unroll
      for (int mi = 0; mi < 2; mi++)
#pragma unroll
        for (int gi = 0; gi < 4; gi++)
          acc[mi][gi] = __builtin_amdgcn_mfma_f32_16x16x32_bf16(av[mi], bv[gi], acc[mi][gi], 0, 0, 0);
    }
  }
#pragma unroll
  for (int mi = 0; mi < 2; mi++)
#pragma unroll
    for (int gi = 0; gi < 4; gi++)
#pragma unroll
      for (int r = 0; r < 4; r++)
        red[w][mi * 16 + (l >> 4) * 4 + r][gi * 16 + (l & 15)] = acc[mi][gi][r];
  __syncthreads();
  for (int p = tid; p < 512; p += 256){
    int bi = p >> 4, nn = p & 15, n = ns + nn;
    float iv = 0, fv = 0, gv = 0, ov = 0;
#pragma unroll
    for (int q = 0; q < 4; q++){
      iv += red[q][bi][nn];      fv += red[q][bi][16 + nn];
      gv += red[q][bi][32 + nn]; ov += red[q][bi][48 + nn];
    }
    float co = first ? 0.f : CST[bi * 512 + n];
    float cn = sigm(fv) * co + sigm(iv) * tanhf(gv);
    CST[bi * 512 + n] = cn;
    Z[bi * 1024 + 512 + n] = f2bf(sigm(ov) * tanhf(cn));
  }
}

// ---------------- phase: attention (all 256 wgs; (b,ch); last chunk combines ctx) ----------------

static __device__ void attn_phase(const u16* __restrict__ CNN2, const u16* __restrict__ CNNB,
                                  const u16* __restrict__ Z, float* __restrict__ UB,
                                  float* __restrict__ MZ, u32* __restrict__ READY,
                                  u16* __restrict__ CTXB, float* __restrict__ SM,
                                  u32* __restrict__ smu, int gid){
  int b = gid >> 3, ch = gid & 7;
  int l0 = ch * 98;
  int tid = threadIdx.x, w = tid >> 6, ln = tid & 63;
  float* sc = SM;          // [98]
  float* sred = SM + 104;  // [4]

  float hreg[8];
  {
    s16x8 hv = *(const s16x8*)&Z[b * 1024 + 512 + ln * 8];
#pragma unroll
    for (int j = 0; j < 8; j++) hreg[j] = bf2f((u16)hv[j]);
  }
  float wmax = -1e30f;
  for (int li = w; li < 98; li += 4){
    s16x8 cv = *(const s16x8*)&CNN2[(size_t)(b * 784 + l0 + li) * 512 + ln * 8];
    float d = 0.f;
#pragma unroll
    for (int j = 0; j < 8; j++) d += hreg[j] * bf2f((u16)cv[j]);
#pragma unroll
    for (int m = 1; m < 64; m <<= 1) d += __shfl_xor(d, m, 64);
    if (ln == 0) sc[li] = d;
    wmax = fmaxf(wmax, d);
  }
  if (ln == 0) sred[w] = wmax;
  __syncthreads();
  float M = fmaxf(fmaxf(sred[0], sred[1]), fmaxf(sred[2], sred[3]));
  __syncthreads();
  float s = 0.f;
  if (tid < 98){ float p = __expf(sc[tid] - M); sc[tid] = p; s = p; }
#pragma unroll
  for (int m = 1; m < 64; m <<= 1) s += __shfl_xor(s, m, 64);
  if (ln == 0) sred[w] = s;
  __syncthreads();
  float S = sred[0] + sred[1] + sred[2] + sred[3];

  float u0 = 0.f, u1 = 0.f;
  int e0 = 2 * tid;
  for (int li = 0; li < 98; li++){
    float p = sc[li];
    u32 pw = *(const u32*)&CNNB[(size_t)(b * 784 + l0 + li) * 512 + e0];
    u0 += p * bf2f((u16)(pw & 0xffff));
    u1 += p * bf2f((u16)(pw >> 16));
  }
  float* up = &UB[(size_t)(b * 8 + ch) * 512];
  up[e0] = u0; up[e0 + 1] = u1;
  if (tid == 0){ MZ[(b * 8 + ch) * 2] = M; MZ[(b * 8 + ch) * 2 + 1] = S; }
  __threadfence();
  __syncthreads();
  if (tid == 0) smu[0] = atomicAdd(&READY[b], 1u);
  __syncthreads();
  if ((smu[0] & 7u) == 7u){
    __threadfence();
    float Mg = -1e30f;
#pragma unroll
    for (int k2 = 0; k2 < 8; k2++) Mg = fmaxf(Mg, MZ[(b * 8 + k2) * 2]);
    float Sg = 0.f, al[8];
#pragma unroll
    for (int k2 = 0; k2 < 8; k2++){
      float e = __expf(MZ[(b * 8 + k2) * 2] - Mg);
      al[k2] = e;
      Sg += e * MZ[(b * 8 + k2) * 2 + 1];
    }
    float c0 = 0.f, c1 = 0.f;
#pragma unroll
    for (int k2 = 0; k2 < 8; k2++){
      float a = al[k2] / Sg;
      const float* uq = &UB[(size_t)(b * 8 + k2) * 512];
      c0 += a * uq[e0]; c1 += a * uq[e0 + 1];
    }
    CTXB[b * 512 + e0] = f2bf(c0);
    CTXB[b * 512 + e0 + 1] = f2bf(c1);
  }
}

// ---------------- phase: out(t) = tanh([ctx|h] @ WOUT^T)  (16 wgs, gid 32..47) ----------------

static __device__ void out_phase(const u16* __restrict__ WOUT, const u16* __restrict__ CTXB,
                                 u16* __restrict__ Z, u16* __restrict__ OALL,
                                 float* __restrict__ SM, u32* __restrict__ SYNC,
                                 int gid, int t){
  int tid = threadIdx.x, w = tid >> 6, l = tid & 63;
  int ns = (gid - 32) * 32;
  float (*red)[32][32] = (float(*)[32][32])SM;
  f32x4 acc[2][2];
#pragma unroll
  for (int a = 0; a < 2; a++)
#pragma unroll
    for (int b = 0; b < 2; b++){ f32x4 z = {0.f,0.f,0.f,0.f}; acc[a][b] = z; }
  int kbeg = w * 256;
  for (int k = kbeg; k < kbeg + 256; k += 32){
    int ko = k + (l >> 4) * 8;
    s16x8 av[2], bv[2];
#pragma unroll
    for (int mi = 0; mi < 2; mi++){
      int bi = mi * 16 + (l & 15);
      const u16* src = (ko < 512) ? &CTXB[bi * 512 + ko] : &Z[bi * 1024 + ko];
      av[mi] = *(const s16x8*)src;
    }
#pragma unroll
    for (int ni = 0; ni < 2; ni++)
      bv[ni] = *(const s16x8*)&WOUT[(size_t)(ns + ni * 16 + (l & 15)) * 1024 + ko];
#pragma unroll
    for (int mi = 0; mi < 2; mi++)
#pragma unroll
      for (int ni = 0; ni < 2; ni++)
        acc[mi][ni] = __builtin_amdgcn_mfma_f32_16x16x32_bf16(av[mi], bv[ni], acc[mi][ni], 0, 0, 0);
  }
#pragma unroll
  for (int mi = 0; mi < 2; mi++)
#pragma unroll
    for (int ni = 0; ni < 2; ni++)
#pragma unroll
      for (int r = 0; r < 4; r++)
        red[w][mi * 16 + (l >> 4) * 4 + r][ni * 16 + (l & 15)] = acc[mi][ni][r];
  __syncthreads();
  for (int p = tid; p < 1024; p += 256){
    int bi = p >> 5, nn = p & 31;
    float v = red[0][bi][nn] + red[1][bi][nn] + red[2][bi][nn] + red[3][bi][nn];
    u16 hb = f2bf(tanhf(v));
    int n = ns + nn;
    Z[bi * 1024 + n] = hb;
    OALL[(size_t)(bi * 256 + t) * 512 + n] = hb;
  }
  __syncthreads();
  if (tid == 0){
    __threadfence();
    atomicAdd(&SYNC[SY_OFLG], 1u);
  }
}

// ---------------- persistent decoder ----------------

__global__ __launch_bounds__(256, 2) void k_persist(const u16* __restrict__ WF,
                                                    const u16* __restrict__ XS,
                                                    const u16* __restrict__ CNN2,
                                                    const u16* __restrict__ CNNB,
                                                    const u16* __restrict__ WOUT,
                                                    u16* __restrict__ Z,
                                                    float* __restrict__ CST,
                                                    u16* __restrict__ CTXB,
                                                    float* __restrict__ UB,
                                                    float* __restrict__ MZ,
                                                    u16* __restrict__ OALL,
                                                    u32* __restrict__ SYNC){
  __shared__ __align__(16) float SM[8192];   // 32 KiB, reused per phase
  __shared__ u32 smu[4];
  int gid = blockIdx.x;
  u32 ph = 0;
  if (gid < 32) gates_phase(WF, XS, Z, CST, SYNC, SM, gid, 0, 1);
  gbar(SYNC, gid, ph++);
  for (int t = 0; t < 256; ++t){
    attn_phase(CNN2, CNNB, Z, UB, MZ, &SYNC[SY_RDY], CTXB, SM, smu, gid);
    gbar(SYNC, gid, ph++);
    if (gid >= 32 && gid < 48)      out_phase(WOUT, CTXB, Z, OALL, SM, SYNC, gid, t);
    else if (gid < 32 && t < 255)   gates_phase(WF, XS, Z, CST, SYNC, SM, gid, t + 1, 0);
    gbar(SYNC, gid, ph++);
  }
}

// ---------------- log_softmax ----------------

__global__ __launch_bounds__(256) void k_lsm(float* __restrict__ x){
  size_t base = (size_t)blockIdx.x * 8000;
  int tid = threadIdx.x, w = tid >> 6, ln = tid & 63;
  __shared__ float sred[4];
  float m = -1e30f;
  for (int v = tid; v < 8000; v += 256) m = fmaxf(m, x[base + v]);
#pragma unroll
  for (int mk = 1; mk < 64; mk <<= 1) m = fmaxf(m, __shfl_xor(m, mk, 64));
  if (ln == 0) sred[w] = m;
  __syncthreads();
  float M = fmaxf(fmaxf(sred[0], sred[1]), fmaxf(sred[2], sred[3]));
  __syncthreads();
  float s = 0.f;
  for (int v = tid; v < 8000; v += 256) s += __expf(x[base + v] - M);
#pragma unroll
  for (int mk = 1; mk < 64; mk <<= 1) s += __shfl_xor(s, mk, 64);
  if (ln == 0) sred[w] = s;
  __syncthreads();
  float S = sred[0] + sred[1] + sred[2] + sred[3];
  float lz = M + logf(S);
  for (int v = tid; v < 8000; v += 256) x[base + v] -= lz;
}

// ---------------- launcher ----------------

extern "C" void kernel_launch(void* const* d_in, const int* in_sizes, int n_in,
                              void* d_out, int out_size, void* d_ws, size_t ws_size,
                              hipStream_t stream){
  const float* cnn  = (const float*)d_in[0];
  const int*   seq  = (const int*)d_in[1];
  const float* emb  = (const float*)d_in[2];
  const float* wih  = (const float*)d_in[3];
  const float* whh  = (const float*)d_in[4];
  const float* whm  = (const float*)d_in[5];
  const float* wo   = (const float*)d_in[6];
  const float* wlg  = (const float*)d_in[7];
  const float* blg  = (const float*)d_in[8];

  char* ws = (char*)d_ws;
  u16*   WF     = (u16*)(ws + 0);          // 2048x1280 bf16
  u16*   WHMT   = (u16*)(ws + 5242880);    // 512x512 bf16
  u16*   WOUT   = (u16*)(ws + 5767168);    // 512x1024 bf16
  u16*   WLOGIT = (u16*)(ws + 6815744);    // 8000x512 bf16
  u16*   CNNBF  = (u16*)(ws + 15007744);   // 25088x512 bf16
  u16*   CNN2   = (u16*)(ws + 40697856);   // 25088x512 bf16
  u16*   XS     = (u16*)(ws + 66387968);   // 8192x256 bf16
  u16*   OALL   = (u16*)(ws + 70582272);   // 8192x512 bf16
  u16*   Z      = (u16*)(ws + 78970880);   // 32x1024 bf16  [out|h]
  u32*   SYNC   = (u32*)(ws + 79036416);   // 8 KiB sync area
  float* CST    = (float*)(ws + 79101952); // 32x512 f32
  u16*   CTXB   = (u16*)(ws + 79167488);   // 32x512 bf16
  float* UB     = (float*)(ws + 79200256); // 32x8x512 f32
  float* MZ     = (float*)(ws + 79724544); // 32x8x2 f32

  float* OUT = (float*)d_out;

  hipMemsetAsync(SYNC, 0, 8192, stream);
  k_wfull<<<512, 256, 0, stream>>>(wih, whh, WF);
  k_whmt<<<256, 256, 0, stream>>>(whm, WHMT);
  k_cvt<<<512, 256, 0, stream>>>(wo, WOUT, 512 * 1024);
  k_cvt<<<2048, 256, 0, stream>>>(wlg, WLOGIT, 8000 * 512);
  k_cvt<<<2048, 256, 0, stream>>>(cnn, CNNBF, 25088 * 512);
  k_xs<<<2048, 256, 0, stream>>>(seq, emb, XS);

  {
    dim3 g(196, 4);
    k_gemm<1, 0, 0><<<g, 256, 0, stream>>>(CNNBF, WHMT, CNN2, nullptr, 25088, 512, 512);
  }

  k_persist<<<256, 256, 0, stream>>>(WF, XS, CNN2, CNNBF, WOUT, Z, CST, CTXB, UB, MZ, OALL, SYNC);

  {
    dim3 g(64, 63);
    k_gemm<0, 1, 1><<<g, 256, 0, stream>>>(OALL, WLOGIT, OUT, blg, 8192, 8000, 512);
  }
  k_lsm<<<8192, 256, 0, stream>>>(OUT);
}

// Round 4
// 16691.797 us; speedup vs baseline: 1.1879x; 1.1879x over previous
//
#include <hip/hip_runtime.h>
#include <hip/hip_bf16.h>
#include <stdint.h>

typedef unsigned short u16;
typedef unsigned int u32;
typedef __attribute__((ext_vector_type(8))) short s16x8;
typedef __attribute__((ext_vector_type(4))) float f32x4;

static __device__ __forceinline__ float bf2f(u16 u){
  unsigned v = ((unsigned)u) << 16; return __builtin_bit_cast(float, v);
}
static __device__ __forceinline__ u16 f2bf(float f){
  unsigned u = __builtin_bit_cast(unsigned, f);
  u += 0x7FFFu + ((u >> 16) & 1u);
  return (u16)(u >> 16);
}
static __device__ __forceinline__ float sigm(float x){ return 1.f / (1.f + __expf(-x)); }

typedef __attribute__((address_space(1))) const u32 gu32;
typedef __attribute__((address_space(3))) u32 lu32;
static __device__ __forceinline__ void gload_lds16(const void* g, void* l){
  __builtin_amdgcn_global_load_lds((gu32*)g, (lu32*)l, 16, 0, 0);
}

// SYNC (u32 idx): READY[b]=b*16 (b<32); OUTFLAG=512; HFLAG=528; MFLAG=544; CTXDONE=560
#define SY_RDY   0
#define SY_OFLG  512
#define SY_HFLAG 528
#define SY_MFLAG 544
#define SY_CTXD  560

static __device__ __forceinline__ void flag_bump(u32* f){
  __threadfence();
  atomicAdd(f, 1u);
}
static __device__ __forceinline__ void flag_wait(u32* f, u32 target){
  if (threadIdx.x == 0){
    while (__hip_atomic_load(f, __ATOMIC_RELAXED, __HIP_MEMORY_SCOPE_AGENT) < target)
      __builtin_amdgcn_s_sleep(1);
    __threadfence();
  }
  __syncthreads();
}

// ---------------- prep kernels ----------------

__global__ __launch_bounds__(256) void k_wfull(const float* __restrict__ wih,
                                               const float* __restrict__ whh,
                                               u16* __restrict__ wf){
  int stride = gridDim.x * blockDim.x;
  for (int i = blockIdx.x * blockDim.x + threadIdx.x; i < 2048 * 1280; i += stride){
    int j = i / 1280, k = i - j * 1280;
    float v = (k < 768) ? wih[j * 768 + k] : whh[j * 512 + (k - 768)];
    wf[i] = f2bf(v);
  }
}

__global__ __launch_bounds__(256) void k_cvt(const float* __restrict__ s,
                                             u16* __restrict__ d, int n){
  int stride = gridDim.x * blockDim.x * 4;
  for (int i = (blockIdx.x * blockDim.x + threadIdx.x) * 4; i < n; i += stride){
    float4 v = *(const float4*)&s[i];
    d[i + 0] = f2bf(v.x); d[i + 1] = f2bf(v.y);
    d[i + 2] = f2bf(v.z); d[i + 3] = f2bf(v.w);
  }
}

// xs stored [t][b][e] for per-step locality
__global__ __launch_bounds__(256) void k_xs(const int* __restrict__ seq,
                                            const float* __restrict__ emb,
                                            u16* __restrict__ xs){
  int stride = gridDim.x * blockDim.x;
  for (int i = blockIdx.x * blockDim.x + threadIdx.x; i < 8192 * 256; i += stride){
    int m = i >> 8, e = i & 255;          // m = b*256 + t
    int b = m >> 8, t = m & 255;
    float v = emb[(size_t)seq[m] * 256 + e];
    xs[(size_t)(t * 32 + b) * 256 + e] = f2bf(v > 0.f ? v : 0.f);
  }
}

// ---------------- 128x128 bf16 MFMA GEMM: C = A[M,K] @ B[N,K]^T ----------------

template<int OUTBF, int HASBIAS, int NG>
__global__ __launch_bounds__(256) void k_gemm(const u16* __restrict__ A,
                                              const u16* __restrict__ Bm,
                                              void* __restrict__ Cout,
                                              const float* __restrict__ bias,
                                              int M, int N, int K){
  __shared__ __align__(16) u16 As[128 * 64];
  __shared__ __align__(16) u16 Bs[128 * 64];
  int tid = threadIdx.x; int w = tid >> 6; int l = tid & 63;
  int m0 = blockIdx.x * 128, n0 = blockIdx.y * 128;
  int wr = w >> 1, wc = w & 1;
  f32x4 acc[4][4];
#pragma unroll
  for (int a = 0; a < 4; a++)
#pragma unroll
    for (int b = 0; b < 4; b++){ f32x4 z = {0.f,0.f,0.f,0.f}; acc[a][b] = z; }
  int rA = m0 + (tid >> 3);
  int rB = n0 + (tid >> 3);
  for (int k0 = 0; k0 < K; k0 += 64){
    __syncthreads();
    int ca = k0 + (tid & 7) * 8;
#pragma unroll
    for (int i = 0; i < 4; i++){
      gload_lds16(&A[(size_t)(rA + i * 32) * K + ca], &As[i * 2048 + w * 512]);
      int rb = rB + i * 32;
      if (NG) rb = (rb < N - 1) ? rb : (N - 1);
      gload_lds16(&Bm[(size_t)rb * K + ca], &Bs[i * 2048 + w * 512]);
    }
    asm volatile("s_waitcnt vmcnt(0)" ::: "memory");
    __syncthreads();
#pragma unroll
    for (int ks = 0; ks < 2; ks++){
      s16x8 av[4], bv[4];
      int ko = ks * 32 + (l >> 4) * 8;
#pragma unroll
      for (int i = 0; i < 4; i++) av[i] = *(const s16x8*)&As[(wr * 64 + i * 16 + (l & 15)) * 64 + ko];
#pragma unroll
      for (int i = 0; i < 4; i++) bv[i] = *(const s16x8*)&Bs[(wc * 64 + i * 16 + (l & 15)) * 64 + ko];
#pragma unroll
      for (int mi = 0; mi < 4; mi++)
#pragma unroll
        for (int ni = 0; ni < 4; ni++)
          acc[mi][ni] = __builtin_amdgcn_mfma_f32_16x16x32_bf16(av[mi], bv[ni], acc[mi][ni], 0, 0, 0);
    }
  }
#pragma unroll
  for (int mi = 0; mi < 4; mi++)
#pragma unroll
    for (int ni = 0; ni < 4; ni++){
      int row = m0 + wr * 64 + mi * 16 + (l >> 4) * 4;
      int col = n0 + wc * 64 + ni * 16 + (l & 15);
      if (NG && col >= N) continue;
#pragma unroll
      for (int r = 0; r < 4; r++){
        float v = acc[mi][ni][r];
        if (HASBIAS) v += bias[col];
        if (OUTBF) ((u16*)Cout)[(size_t)(row + r) * N + col] = f2bf(v);
        else       ((float*)Cout)[(size_t)(row + r) * N + col] = v;
      }
    }
}

// ---------------- gates + LSTM for step tn (32 wgs, gid<32) ----------------
// gates(tn) = [x(tn) | out(tn-1) | h(tn-1)] @ WF^T; x,h first, spin OUTFLAG, out-seg.

static __device__ void gates_phase(const u16* __restrict__ WF, const u16* __restrict__ XS,
                                   const u16* __restrict__ Zp, u16* __restrict__ Zn,
                                   float* __restrict__ CST, u32* __restrict__ SYNC,
                                   float* __restrict__ SM, int gid, int tn, int first){
  int tid = threadIdx.x, w = tid >> 6, l = tid & 63;
  int ns = gid << 4;
  float (*red)[32][64] = (float(*)[32][64])SM;
  f32x4 acc[2][4];
#pragma unroll
  for (int a = 0; a < 2; a++)
#pragma unroll
    for (int b = 0; b < 4; b++){ f32x4 z = {0.f,0.f,0.f,0.f}; acc[a][b] = z; }

  // x segment: K [0,256), per-wave 64
  for (int k = w * 64; k < w * 64 + 64; k += 32){
    int ko = k + (l >> 4) * 8;
    s16x8 av[2], bv[4];
#pragma unroll
    for (int mi = 0; mi < 2; mi++){
      int bi = mi * 16 + (l & 15);
      av[mi] = *(const s16x8*)&XS[(size_t)(tn * 32 + bi) * 256 + ko];
    }
#pragma unroll
    for (int gi = 0; gi < 4; gi++)
      bv[gi] = *(const s16x8*)&WF[(size_t)(gi * 512 + ns + (l & 15)) * 1280 + ko];
#pragma unroll
    for (int mi = 0; mi < 2; mi++)
#pragma unroll
      for (int gi = 0; gi < 4; gi++)
        acc[mi][gi] = __builtin_amdgcn_mfma_f32_16x16x32_bf16(av[mi], bv[gi], acc[mi][gi], 0, 0, 0);
  }
  if (!first){
    // h segment: K [768,1280)
    for (int k = 768 + w * 128; k < 768 + w * 128 + 128; k += 32){
      int ko = k + (l >> 4) * 8;
      s16x8 av[2], bv[4];
#pragma unroll
      for (int mi = 0; mi < 2; mi++){
        int bi = mi * 16 + (l & 15);
        av[mi] = *(const s16x8*)&Zp[(size_t)bi * 1024 + (ko - 256)];
      }
#pragma unroll
      for (int gi = 0; gi < 4; gi++)
        bv[gi] = *(const s16x8*)&WF[(size_t)(gi * 512 + ns + (l & 15)) * 1280 + ko];
#pragma unroll
      for (int mi = 0; mi < 2; mi++)
#pragma unroll
        for (int gi = 0; gi < 4; gi++)
          acc[mi][gi] = __builtin_amdgcn_mfma_f32_16x16x32_bf16(av[mi], bv[gi], acc[mi][gi], 0, 0, 0);
    }
    // wait out(tn-1) complete
    flag_wait(&SYNC[SY_OFLG], 16u * (u32)tn);
    // out segment: K [256,768)
    for (int k = 256 + w * 128; k < 256 + w * 128 + 128; k += 32){
      int ko = k + (l >> 4) * 8;
      s16x8 av[2], bv[4];
#pragma unroll
      for (int mi = 0; mi < 2; mi++){
        int bi = mi * 16 + (l & 15);
        av[mi] = *(const s16x8*)&Zp[(size_t)bi * 1024 + (ko - 256)];
      }
#pragma unroll
      for (int gi = 0; gi < 4; gi++)
        bv[gi] = *(const s16x8*)&WF[(size_t)(gi * 512 + ns + (l & 15)) * 1280 + ko];
#pragma unroll
      for (int mi = 0; mi < 2; mi++)
#pragma unroll
        for (int gi = 0; gi < 4; gi++)
          acc[mi][gi] = __builtin_amdgcn_mfma_f32_16x16x32_bf16(av[mi], bv[gi], acc[mi][gi], 0, 0, 0);
    }
  }
#pragma unroll
  for (int mi = 0; mi < 2; mi++)
#pragma unroll
    for (int gi = 0; gi < 4; gi++)
#pragma unroll
      for (int r = 0; r < 4; r++)
        red[w][mi * 16 + (l >> 4) * 4 + r][gi * 16 + (l & 15)] = acc[mi][gi][r];
  __syncthreads();
  for (int p = tid; p < 512; p += 256){
    int bi = p >> 4, nn = p & 15, n = ns + nn;
    float iv = 0, fv = 0, gv = 0, ov = 0;
#pragma unroll
    for (int q = 0; q < 4; q++){
      iv += red[q][bi][nn];      fv += red[q][bi][16 + nn];
      gv += red[q][bi][32 + nn]; ov += red[q][bi][48 + nn];
    }
    float co = first ? 0.f : CST[bi * 512 + n];
    float cn = sigm(fv) * co + sigm(iv) * tanhf(gv);
    CST[bi * 512 + n] = cn;
    Zn[bi * 1024 + 512 + n] = f2bf(sigm(ov) * tanhf(cn));
  }
  __syncthreads();
  if (tid == 0) flag_bump(&SYNC[SY_HFLAG]);
}

// ---------------- mapped(tn) = h(tn) @ w_hm^T  (32 wgs; 16 cols each) ----------------

static __device__ void mapped_phase(const u16* __restrict__ WHMB, const u16* __restrict__ Zn,
                                    float* __restrict__ MAPn, u32* __restrict__ SYNC,
                                    float* __restrict__ SM, int gid, int tn){
  flag_wait(&SYNC[SY_HFLAG], 32u * (u32)(tn + 1));
  int tid = threadIdx.x, w = tid >> 6, l = tid & 63;
  float (*red)[32][16] = (float(*)[32][16])SM;
  f32x4 acc[2];
  { f32x4 z = {0.f,0.f,0.f,0.f}; acc[0] = z; acc[1] = z; }
  for (int k = w * 128; k < w * 128 + 128; k += 32){
    int ko = k + (l >> 4) * 8;
    s16x8 av[2], bv;
#pragma unroll
    for (int mi = 0; mi < 2; mi++){
      int bi = mi * 16 + (l & 15);
      av[mi] = *(const s16x8*)&Zn[(size_t)bi * 1024 + 512 + ko];
    }
    bv = *(const s16x8*)&WHMB[(size_t)(gid * 16 + (l & 15)) * 512 + ko];
#pragma unroll
    for (int mi = 0; mi < 2; mi++)
      acc[mi] = __builtin_amdgcn_mfma_f32_16x16x32_bf16(av[mi], bv, acc[mi], 0, 0, 0);
  }
#pragma unroll
  for (int mi = 0; mi < 2; mi++)
#pragma unroll
    for (int r = 0; r < 4; r++)
      red[w][mi * 16 + (l >> 4) * 4 + r][l & 15] = acc[mi][r];
  __syncthreads();
  for (int p = tid; p < 512; p += 256){
    int bi = p >> 4, nn = p & 15;
    MAPn[bi * 512 + gid * 16 + nn] =
      red[0][bi][nn] + red[1][bi][nn] + red[2][bi][nn] + red[3][bi][nn];
  }
  __syncthreads();
  if (tid == 0) flag_bump(&SYNC[SY_MFLAG]);
}

// ---------------- attention step t (all 256 wgs; (b,ch); register-resident rows) ----------------

static __device__ void attn_phase(const u16* __restrict__ CNNB, const float* __restrict__ MAPp,
                                  float* __restrict__ UBp, float* __restrict__ MZp,
                                  u16* __restrict__ CTXBp, u32* __restrict__ SYNC,
                                  float* __restrict__ SM, u32* __restrict__ smu,
                                  int gid, int t){
  flag_wait(&SYNC[SY_MFLAG], 32u * (u32)(t + 1));
  int b = gid >> 3, ch = gid & 7;
  int l0 = ch * 98;
  int tid = threadIdx.x, w = tid >> 6, ln = tid & 63;
  float* sc   = SM;        // [98]
  float* sred = SM + 100;  // [4]
  float* accw = SM + 112;  // [4][512]

  float mp[8];
  {
    f32x4 a = *(const f32x4*)&MAPp[b * 512 + ln * 8];
    f32x4 c = *(const f32x4*)&MAPp[b * 512 + ln * 8 + 4];
    mp[0]=a[0]; mp[1]=a[1]; mp[2]=a[2]; mp[3]=a[3];
    mp[4]=c[0]; mp[5]=c[1]; mp[6]=c[2]; mp[7]=c[3];
  }
  // load 25 rows into registers (rows w, w+4, ..., guarded)
  s16x8 rowv[25];
  const u16* base = &CNNB[((size_t)(b * 784 + l0)) * 512 + ln * 8];
#pragma unroll
  for (int i = 0; i < 25; i++){
    int li = w + 4 * i;
    if (li < 98) rowv[i] = *(const s16x8*)(base + (size_t)li * 512);
  }
  // pass 1: scores
  float wmax = -1e30f;
#pragma unroll
  for (int i = 0; i < 25; i++){
    int li = w + 4 * i;
    if (li < 98){
      float d = 0.f;
#pragma unroll
      for (int j = 0; j < 8; j++) d = fmaf(mp[j], bf2f((u16)rowv[i][j]), d);
#pragma unroll
      for (int m = 1; m < 64; m <<= 1) d += __shfl_xor(d, m, 64);
      if (ln == 0) sc[li] = d;
      wmax = fmaxf(wmax, d);
    }
  }
  if (ln == 0) sred[w] = wmax;
  __syncthreads();
  float M = fmaxf(fmaxf(sred[0], sred[1]), fmaxf(sred[2], sred[3]));
  __syncthreads();
  float s = 0.f;
  if (tid < 98){ float p = __expf(sc[tid] - M); sc[tid] = p; s = p; }
#pragma unroll
  for (int m = 1; m < 64; m <<= 1) s += __shfl_xor(s, m, 64);
  if (ln == 0) sred[w] = s;
  __syncthreads();
  float S = sred[0] + sred[1] + sred[2] + sred[3];
  // pass 2: weighted sum from registers
  float acc[8] = {0.f,0.f,0.f,0.f,0.f,0.f,0.f,0.f};
#pragma unroll
  for (int i = 0; i < 25; i++){
    int li = w + 4 * i;
    if (li < 98){
      float p = sc[li];
#pragma unroll
      for (int j = 0; j < 8; j++) acc[j] = fmaf(p, bf2f((u16)rowv[i][j]), acc[j]);
    }
  }
  {
    f32x4 a = {acc[0], acc[1], acc[2], acc[3]};
    f32x4 c = {acc[4], acc[5], acc[6], acc[7]};
    *(f32x4*)&accw[w * 512 + ln * 8]     = a;
    *(f32x4*)&accw[w * 512 + ln * 8 + 4] = c;
  }
  __syncthreads();
  int e0 = 2 * tid;
  float u0 = accw[e0] + accw[512 + e0] + accw[1024 + e0] + accw[1536 + e0];
  float u1 = accw[e0 + 1] + accw[512 + e0 + 1] + accw[1024 + e0 + 1] + accw[1536 + e0 + 1];
  float* up = &UBp[(size_t)(b * 8 + ch) * 512];
  up[e0] = u0; up[e0 + 1] = u1;
  if (tid == 0){ MZp[(b * 8 + ch) * 2] = M; MZp[(b * 8 + ch) * 2 + 1] = S; }
  __threadfence();
  __syncthreads();
  if (tid == 0) smu[0] = atomicAdd(&SYNC[SY_RDY + b * 16], 1u);
  __syncthreads();
  if ((smu[0] & 7u) == 7u){
    __threadfence();
    float Mg = -1e30f;
#pragma unroll
    for (int k2 = 0; k2 < 8; k2++) Mg = fmaxf(Mg, MZp[(b * 8 + k2) * 2]);
    float Sg = 0.f, al[8];
#pragma unroll
    for (int k2 = 0; k2 < 8; k2++){
      float e = __expf(MZp[(b * 8 + k2) * 2] - Mg);
      al[k2] = e;
      Sg += e * MZp[(b * 8 + k2) * 2 + 1];
    }
    float c0 = 0.f, c1 = 0.f;
#pragma unroll
    for (int k2 = 0; k2 < 8; k2++){
      float a = al[k2] / Sg;
      const float* uq = &UBp[(size_t)(b * 8 + k2) * 512];
      c0 += a * uq[e0]; c1 += a * uq[e0 + 1];
    }
    CTXBp[b * 512 + e0] = f2bf(c0);
    CTXBp[b * 512 + e0 + 1] = f2bf(c1);
    __syncthreads();
    if (tid == 0) flag_bump(&SYNC[SY_CTXD]);
  }
}

// ---------------- out(t) = tanh([ctx|h] @ WOUT^T)  (16 wgs) ----------------

static __device__ void out_phase(const u16* __restrict__ WOUT, const u16* __restrict__ CTXBp,
                                 u16* __restrict__ Zp, u16* __restrict__ OALL,
                                 float* __restrict__ SM, u32* __restrict__ SYNC,
                                 int og, int t){
  flag_wait(&SYNC[SY_CTXD], 32u * (u32)(t + 1));
  int tid = threadIdx.x, w = tid >> 6, l = tid & 63;
  int ns = og * 32;
  float (*red)[32][32] = (float(*)[32][32])SM;
  f32x4 acc[2][2];
#pragma unroll
  for (int a = 0; a < 2; a++)
#pragma unroll
    for (int b = 0; b < 2; b++){ f32x4 z = {0.f,0.f,0.f,0.f}; acc[a][b] = z; }
  int kbeg = w * 256;
  for (int k = kbeg; k < kbeg + 256; k += 32){
    int ko = k + (l >> 4) * 8;
    s16x8 av[2], bv[2];
#pragma unroll
    for (int mi = 0; mi < 2; mi++){
      int bi = mi * 16 + (l & 15);
      const u16* src = (ko < 512) ? &CTXBp[bi * 512 + ko] : &Zp[bi * 1024 + ko];
      av[mi] = *(const s16x8*)src;
    }
#pragma unroll
    for (int ni = 0; ni < 2; ni++)
      bv[ni] = *(const s16x8*)&WOUT[(size_t)(ns + ni * 16 + (l & 15)) * 1024 + ko];
#pragma unroll
    for (int mi = 0; mi < 2; mi++)
#pragma unroll
      for (int ni = 0; ni < 2; ni++)
        acc[mi][ni] = __builtin_amdgcn_mfma_f32_16x16x32_bf16(av[mi], bv[ni], acc[mi][ni], 0, 0, 0);
  }
#pragma unroll
  for (int mi = 0; mi < 2; mi++)
#pragma unroll
    for (int ni = 0; ni < 2; ni++)
#pragma unroll
      for (int r = 0; r < 4; r++)
        red[w][mi * 16 + (l >> 4) * 4 + r][ni * 16 + (l & 15)] = acc[mi][ni][r];
  __syncthreads();
  for (int p = tid; p < 1024; p += 256){
    int bi = p >> 5, nn = p & 31;
    float v = red[0][bi][nn] + red[1][bi][nn] + red[2][bi][nn] + red[3][bi][nn];
    u16 hb = f2bf(tanhf(v));
    int n = ns + nn;
    Zp[bi * 1024 + n] = hb;
    OALL[(size_t)(bi * 256 + t) * 512 + n] = hb;
  }
  __syncthreads();
  if (tid == 0) flag_bump(&SYNC[SY_OFLG]);
}

// ---------------- persistent decoder: flag-driven, no grid barriers ----------------

__global__ __launch_bounds__(256, 1) void k_persist(const u16* __restrict__ WF,
                                                    const u16* __restrict__ XS,
                                                    const u16* __restrict__ CNNB,
                                                    const u16* __restrict__ WHMB,
                                                    const u16* __restrict__ WOUT,
                                                    u16* __restrict__ Z,
                                                    float* __restrict__ CST,
                                                    u16* __restrict__ CTXB,
                                                    float* __restrict__ UB,
                                                    float* __restrict__ MZ,
                                                    float* __restrict__ MAPPED,
                                                    u16* __restrict__ OALL,
                                                    u32* __restrict__ SYNC){
  __shared__ __align__(16) float SM[8192];
  __shared__ u32 smu[1];
  int gid = blockIdx.x;

  if (gid < 32){
    gates_phase(WF, XS, Z, Z + 0, CST, SYNC, SM, gid, 0, 1);        // h(0) -> parity 0
    mapped_phase(WHMB, Z + 0, MAPPED, SYNC, SM, gid, 0);            // mapped(0) -> parity 0
  }
  for (int t = 0; t < 256; ++t){
    int par = t & 1, nxt = (t + 1) & 1;
    attn_phase(CNNB, MAPPED + par * 16384,
               UB + par * 131072, MZ + par * 512,
               CTXB + par * 16384, SYNC, SM, smu, gid, t);
    if (gid >= 32 && gid < 48){
      out_phase(WOUT, CTXB + par * 16384, Z + par * 32768, OALL, SM, SYNC, gid - 32, t);
    } else if (gid < 32 && t < 255){
      gates_phase(WF, XS, Z + par * 32768, Z + nxt * 32768, CST, SYNC, SM, gid, t + 1, 0);
      mapped_phase(WHMB, Z + nxt * 32768, MAPPED + nxt * 16384, SYNC, SM, gid, t + 1);
    }
  }
}

// ---------------- log_softmax ----------------

__global__ __launch_bounds__(256) void k_lsm(float* __restrict__ x){
  size_t base = (size_t)blockIdx.x * 8000;
  int tid = threadIdx.x, w = tid >> 6, ln = tid & 63;
  __shared__ float sred[4];
  float m = -1e30f;
  for (int v = tid; v < 8000; v += 256) m = fmaxf(m, x[base + v]);
#pragma unroll
  for (int mk = 1; mk < 64; mk <<= 1) m = fmaxf(m, __shfl_xor(m, mk, 64));
  if (ln == 0) sred[w] = m;
  __syncthreads();
  float M = fmaxf(fmaxf(sred[0], sred[1]), fmaxf(sred[2], sred[3]));
  __syncthreads();
  float s = 0.f;
  for (int v = tid; v < 8000; v += 256) s += __expf(x[base + v] - M);
#pragma unroll
  for (int mk = 1; mk < 64; mk <<= 1) s += __shfl_xor(s, mk, 64);
  if (ln == 0) sred[w] = s;
  __syncthreads();
  float S = sred[0] + sred[1] + sred[2] + sred[3];
  float lz = M + logf(S);
  for (int v = tid; v < 8000; v += 256) x[base + v] -= lz;
}

// ---------------- launcher ----------------

extern "C" void kernel_launch(void* const* d_in, const int* in_sizes, int n_in,
                              void* d_out, int out_size, void* d_ws, size_t ws_size,
                              hipStream_t stream){
  const float* cnn  = (const float*)d_in[0];
  const int*   seq  = (const int*)d_in[1];
  const float* emb  = (const float*)d_in[2];
  const float* wih  = (const float*)d_in[3];
  const float* whh  = (const float*)d_in[4];
  const float* whm  = (const float*)d_in[5];
  const float* wo   = (const float*)d_in[6];
  const float* wlg  = (const float*)d_in[7];
  const float* blg  = (const float*)d_in[8];

  char* ws = (char*)d_ws;
  u16*   WF     = (u16*)(ws + 0);          // 2048x1280 bf16 = 5,242,880
  u16*   WHMB   = (u16*)(ws + 5242880);    // 512x512 bf16   =   524,288
  u16*   WOUT   = (u16*)(ws + 5767168);    // 512x1024 bf16  = 1,048,576
  u16*   WLOGIT = (u16*)(ws + 6815744);    // 8000x512 bf16  = 8,192,000
  u16*   CNNBF  = (u16*)(ws + 15007744);   // 25088x512 bf16 = 25,690,112
  u16*   XS     = (u16*)(ws + 40697856);   // [256][32][256] bf16 = 4,194,304
  u16*   OALL   = (u16*)(ws + 44892160);   // 8192x512 bf16  = 8,388,608
  u16*   Z      = (u16*)(ws + 53280768);   // [2][32][1024] bf16 = 131,072
  float* CST    = (float*)(ws + 53411840); // 32x512 f32     = 65,536
  u16*   CTXB   = (u16*)(ws + 53477376);   // [2][32][512] bf16 = 65,536
  float* UB     = (float*)(ws + 53542912); // [2][32][8][512] f32 = 1,048,576
  float* MZ     = (float*)(ws + 54591488); // [2][32][8][2] f32 = 4,096
  float* MAPPED = (float*)(ws + 54595584); // [2][32][512] f32 = 131,072
  u32*   SYNC   = (u32*)(ws + 54726656);   // 8 KiB -> ends 54,734,848

  float* OUT = (float*)d_out;

  hipMemsetAsync(SYNC, 0, 8192, stream);
  k_wfull<<<512, 256, 0, stream>>>(wih, whh, WF);
  k_cvt<<<128, 256, 0, stream>>>(whm, WHMB, 512 * 512);
  k_cvt<<<512, 256, 0, stream>>>(wo, WOUT, 512 * 1024);
  k_cvt<<<2048, 256, 0, stream>>>(wlg, WLOGIT, 8000 * 512);
  k_cvt<<<2048, 256, 0, stream>>>(cnn, CNNBF, 25088 * 512);
  k_xs<<<2048, 256, 0, stream>>>(seq, emb, XS);

  k_persist<<<256, 256, 0, stream>>>(WF, XS, CNNBF, WHMB, WOUT, Z, CST, CTXB, UB, MZ, MAPPED, OALL, SYNC);

  {
    dim3 g(64, 63);
    k_gemm<0, 1, 1><<<g, 256, 0, stream>>>(OALL, WLOGIT, OUT, blg, 8192, 8000, 512);
  }
  k_lsm<<<8192, 256, 0, stream>>>(OUT);
}

// Round 5
// 14465.289 us; speedup vs baseline: 1.3708x; 1.1539x over previous
//
#include <hip/hip_runtime.h>
#include <hip/hip_bf16.h>
#include <stdint.h>

typedef unsigned short u16;
typedef unsigned int u32;
typedef unsigned long long u64;
typedef __attribute__((ext_vector_type(8))) short s16x8;
typedef __attribute__((ext_vector_type(4))) float f32x4;

#define SCOPE_AGENT __HIP_MEMORY_SCOPE_AGENT

static __device__ __forceinline__ float bf2f(u16 u){
  unsigned v = ((unsigned)u) << 16; return __builtin_bit_cast(float, v);
}
static __device__ __forceinline__ u16 f2bf(float f){
  unsigned u = __builtin_bit_cast(unsigned, f);
  u += 0x7FFFu + ((u >> 16) & 1u);
  return (u16)(u >> 16);
}
static __device__ __forceinline__ float sigm(float x){ return 1.f / (1.f + __expf(-x)); }

typedef __attribute__((address_space(1))) const u32 gu32;
typedef __attribute__((address_space(3))) u32 lu32;
static __device__ __forceinline__ void gload_lds16(const void* g, void* l){
  __builtin_amdgcn_global_load_lds((gu32*)g, (lu32*)l, 16, 0, 0);
}

// coherent 16B load via two 8B agent-scope atomic loads (bypasses stale L1/L2)
static __device__ __forceinline__ s16x8 aload16(const u16* p){
  union { u64 q[2]; s16x8 v; } u;
  u.q[0] = __hip_atomic_load((const u64*)p,     __ATOMIC_RELAXED, SCOPE_AGENT);
  u.q[1] = __hip_atomic_load(((const u64*)p)+1, __ATOMIC_RELAXED, SCOPE_AGENT);
  return u.v;
}

// SYNC u32 indices
#define SY_RDY 0     // [32] per-batch arrival counters (free-running, 7/step)
#define SY_GF  64    // h-ready, 32 bumps/step
#define SY_MF  128   // mapped-ready, 32 bumps/step
#define SY_OF  192   // out-ready, 32 bumps/step

static __device__ __forceinline__ void flag_wait(u32* f, u32 target){
  if (threadIdx.x == 0){
    int it = 0;
    for (;;){
      u32 v = ((++it) & 15)
        ? __hip_atomic_load(f, __ATOMIC_RELAXED, SCOPE_AGENT)
        : __hip_atomic_fetch_add(f, 0u, __ATOMIC_RELAXED, SCOPE_AGENT);
      if (v >= target) break;
      __builtin_amdgcn_s_sleep(8);
    }
  }
  __syncthreads();
}
// all threads drain their stores, then one RELEASE bump
static __device__ __forceinline__ void bump_rel(u32* f){
  asm volatile("s_waitcnt vmcnt(0)" ::: "memory");
  __syncthreads();
  if (threadIdx.x == 0)
    __hip_atomic_fetch_add(f, 1u, __ATOMIC_RELEASE, SCOPE_AGENT);
}

// ---------------- prep kernels ----------------

__global__ __launch_bounds__(256) void k_wfull(const float* __restrict__ wih,
                                               const float* __restrict__ whh,
                                               u16* __restrict__ wf){
  int stride = gridDim.x * blockDim.x;
  for (int i = blockIdx.x * blockDim.x + threadIdx.x; i < 2048 * 1280; i += stride){
    int j = i / 1280, k = i - j * 1280;
    float v = (k < 768) ? wih[j * 768 + k] : whh[j * 512 + (k - 768)];
    wf[i] = f2bf(v);
  }
}

__global__ __launch_bounds__(256) void k_cvt(const float* __restrict__ s,
                                             u16* __restrict__ d, int n){
  int stride = gridDim.x * blockDim.x * 4;
  for (int i = (blockIdx.x * blockDim.x + threadIdx.x) * 4; i < n; i += stride){
    float4 v = *(const float4*)&s[i];
    d[i + 0] = f2bf(v.x); d[i + 1] = f2bf(v.y);
    d[i + 2] = f2bf(v.z); d[i + 3] = f2bf(v.w);
  }
}

// xs stored [t][b][e]
__global__ __launch_bounds__(256) void k_xs(const int* __restrict__ seq,
                                            const float* __restrict__ emb,
                                            u16* __restrict__ xs){
  int stride = gridDim.x * blockDim.x;
  for (int i = blockIdx.x * blockDim.x + threadIdx.x; i < 8192 * 256; i += stride){
    int m = i >> 8, e = i & 255;          // m = b*256 + t
    int b = m >> 8, t = m & 255;
    float v = emb[(size_t)seq[m] * 256 + e];
    xs[(size_t)(t * 32 + b) * 256 + e] = f2bf(v > 0.f ? v : 0.f);
  }
}

// ---------------- 128x128 bf16 MFMA GEMM: C = A[M,K] @ B[N,K]^T ----------------

template<int OUTBF, int HASBIAS, int NG>
__global__ __launch_bounds__(256) void k_gemm(const u16* __restrict__ A,
                                              const u16* __restrict__ Bm,
                                              void* __restrict__ Cout,
                                              const float* __restrict__ bias,
                                              int M, int N, int K){
  __shared__ __align__(16) u16 As[128 * 64];
  __shared__ __align__(16) u16 Bs[128 * 64];
  int tid = threadIdx.x; int w = tid >> 6; int l = tid & 63;
  int m0 = blockIdx.x * 128, n0 = blockIdx.y * 128;
  int wr = w >> 1, wc = w & 1;
  f32x4 acc[4][4];
#pragma unroll
  for (int a = 0; a < 4; a++)
#pragma unroll
    for (int b = 0; b < 4; b++){ f32x4 z = {0.f,0.f,0.f,0.f}; acc[a][b] = z; }
  int rA = m0 + (tid >> 3);
  int rB = n0 + (tid >> 3);
  for (int k0 = 0; k0 < K; k0 += 64){
    __syncthreads();
    int ca = k0 + (tid & 7) * 8;
#pragma unroll
    for (int i = 0; i < 4; i++){
      gload_lds16(&A[(size_t)(rA + i * 32) * K + ca], &As[i * 2048 + w * 512]);
      int rb = rB + i * 32;
      if (NG) rb = (rb < N - 1) ? rb : (N - 1);
      gload_lds16(&Bm[(size_t)rb * K + ca], &Bs[i * 2048 + w * 512]);
    }
    asm volatile("s_waitcnt vmcnt(0)" ::: "memory");
    __syncthreads();
#pragma unroll
    for (int ks = 0; ks < 2; ks++){
      s16x8 av[4], bv[4];
      int ko = ks * 32 + (l >> 4) * 8;
#pragma unroll
      for (int i = 0; i < 4; i++) av[i] = *(const s16x8*)&As[(wr * 64 + i * 16 + (l & 15)) * 64 + ko];
#pragma unroll
      for (int i = 0; i < 4; i++) bv[i] = *(const s16x8*)&Bs[(wc * 64 + i * 16 + (l & 15)) * 64 + ko];
#pragma unroll
      for (int mi = 0; mi < 4; mi++)
#pragma unroll
        for (int ni = 0; ni < 4; ni++)
          acc[mi][ni] = __builtin_amdgcn_mfma_f32_16x16x32_bf16(av[mi], bv[ni], acc[mi][ni], 0, 0, 0);
    }
  }
#pragma unroll
  for (int mi = 0; mi < 4; mi++)
#pragma unroll
    for (int ni = 0; ni < 4; ni++){
      int row = m0 + wr * 64 + mi * 16 + (l >> 4) * 4;
      int col = n0 + wc * 64 + ni * 16 + (l & 15);
      if (NG && col >= N) continue;
#pragma unroll
      for (int r = 0; r < 4; r++){
        float v = acc[mi][ni][r];
        if (HASBIAS) v += bias[col];
        if (OUTBF) ((u16*)Cout)[(size_t)(row + r) * N + col] = f2bf(v);
        else       ((float*)Cout)[(size_t)(row + r) * N + col] = v;
      }
    }
}

// ---------------- gates role (gid<32): gates->LSTM->h ; then mapped ----------------

static __device__ void gates_loop(const u16* __restrict__ WF, const u16* __restrict__ XS,
                                  const u16* __restrict__ WHMB,
                                  u16* __restrict__ Z, float* __restrict__ CST,
                                  float* __restrict__ MAPPED, u32* __restrict__ SYNC,
                                  float* __restrict__ SM, int gid){
  int tid = threadIdx.x, w = tid >> 6, l = tid & 63;
  int ns = gid << 4;
  float (*red)[32][64] = (float(*)[32][64])SM;
  for (int t = 0; t < 256; ++t){
    u16* Zn = Z + (t & 1) * 32768;
    const u16* Zp = Z + ((t + 1) & 1) * 32768;
    f32x4 acc[2][4];
#pragma unroll
    for (int a = 0; a < 2; a++)
#pragma unroll
      for (int b = 0; b < 4; b++){ f32x4 z = {0.f,0.f,0.f,0.f}; acc[a][b] = z; }
    // x segment: K [0,256), per-wave 64 (no wait needed)
    for (int k = w * 64; k < w * 64 + 64; k += 32){
      int ko = k + (l >> 4) * 8;
      s16x8 av[2], bv[4];
#pragma unroll
      for (int mi = 0; mi < 2; mi++){
        int bi = mi * 16 + (l & 15);
        av[mi] = *(const s16x8*)&XS[(size_t)(t * 32 + bi) * 256 + ko];
      }
#pragma unroll
      for (int gi = 0; gi < 4; gi++)
        bv[gi] = *(const s16x8*)&WF[(size_t)(gi * 512 + ns + (l & 15)) * 1280 + ko];
#pragma unroll
      for (int mi = 0; mi < 2; mi++)
#pragma unroll
        for (int gi = 0; gi < 4; gi++)
          acc[mi][gi] = __builtin_amdgcn_mfma_f32_16x16x32_bf16(av[mi], bv[gi], acc[mi][gi], 0, 0, 0);
    }
    if (t > 0){
      flag_wait(&SYNC[SY_GF], 32u * (u32)t);          // h(t-1) ready
      for (int k = 768 + w * 128; k < 768 + w * 128 + 128; k += 32){
        int ko = k + (l >> 4) * 8;
        s16x8 av[2], bv[4];
#pragma unroll
        for (int mi = 0; mi < 2; mi++){
          int bi = mi * 16 + (l & 15);
          av[mi] = aload16(&Zp[(size_t)bi * 1024 + (ko - 256)]);
        }
#pragma unroll
        for (int gi = 0; gi < 4; gi++)
          bv[gi] = *(const s16x8*)&WF[(size_t)(gi * 512 + ns + (l & 15)) * 1280 + ko];
#pragma unroll
        for (int mi = 0; mi < 2; mi++)
#pragma unroll
          for (int gi = 0; gi < 4; gi++)
            acc[mi][gi] = __builtin_amdgcn_mfma_f32_16x16x32_bf16(av[mi], bv[gi], acc[mi][gi], 0, 0, 0);
      }
      flag_wait(&SYNC[SY_OF], 32u * (u32)t);          // out(t-1) ready
      for (int k = 256 + w * 128; k < 256 + w * 128 + 128; k += 32){
        int ko = k + (l >> 4) * 8;
        s16x8 av[2], bv[4];
#pragma unroll
        for (int mi = 0; mi < 2; mi++){
          int bi = mi * 16 + (l & 15);
          av[mi] = aload16(&Zp[(size_t)bi * 1024 + (ko - 256)]);
        }
#pragma unroll
        for (int gi = 0; gi < 4; gi++)
          bv[gi] = *(const s16x8*)&WF[(size_t)(gi * 512 + ns + (l & 15)) * 1280 + ko];
#pragma unroll
        for (int mi = 0; mi < 2; mi++)
#pragma unroll
          for (int gi = 0; gi < 4; gi++)
            acc[mi][gi] = __builtin_amdgcn_mfma_f32_16x16x32_bf16(av[mi], bv[gi], acc[mi][gi], 0, 0, 0);
      }
    }
#pragma unroll
    for (int mi = 0; mi < 2; mi++)
#pragma unroll
      for (int gi = 0; gi < 4; gi++)
#pragma unroll
        for (int r = 0; r < 4; r++)
          red[w][mi * 16 + (l >> 4) * 4 + r][gi * 16 + (l & 15)] = acc[mi][gi][r];
    __syncthreads();
    {
      int bi = tid >> 3, j = (tid & 7) * 2;
      float iv0=0,fv0=0,gv0=0,ov0=0, iv1=0,fv1=0,gv1=0,ov1=0;
#pragma unroll
      for (int q = 0; q < 4; q++){
        iv0 += red[q][bi][j];      fv0 += red[q][bi][16 + j];
        gv0 += red[q][bi][32 + j]; ov0 += red[q][bi][48 + j];
        iv1 += red[q][bi][j + 1];      fv1 += red[q][bi][16 + j + 1];
        gv1 += red[q][bi][32 + j + 1]; ov1 += red[q][bi][48 + j + 1];
      }
      int n0 = ns + j;
      float c0 = (t > 0) ? CST[bi * 512 + n0]     : 0.f;
      float c1 = (t > 0) ? CST[bi * 512 + n0 + 1] : 0.f;
      float cn0 = sigm(fv0) * c0 + sigm(iv0) * tanhf(gv0);
      float cn1 = sigm(fv1) * c1 + sigm(iv1) * tanhf(gv1);
      float h0 = sigm(ov0) * tanhf(cn0);
      float h1 = sigm(ov1) * tanhf(cn1);
      CST[bi * 512 + n0] = cn0; CST[bi * 512 + n0 + 1] = cn1;
      u32 pk = (u32)f2bf(h0) | ((u32)f2bf(h1) << 16);
      __hip_atomic_store((u32*)(Zn + bi * 1024 + 512 + n0), pk, __ATOMIC_RELAXED, SCOPE_AGENT);
    }
    bump_rel(&SYNC[SY_GF]);
    flag_wait(&SYNC[SY_GF], 32u * (u32)(t + 1));      // full h(t) ready
    // mapped(t) = h(t) @ Whm^T, cols [ns,ns+16)
    f32x4 m2[2];
    { f32x4 z = {0.f,0.f,0.f,0.f}; m2[0] = z; m2[1] = z; }
    for (int k = w * 128; k < w * 128 + 128; k += 32){
      int ko = k + (l >> 4) * 8;
      s16x8 av2[2], bv2;
#pragma unroll
      for (int mi = 0; mi < 2; mi++){
        int bi = mi * 16 + (l & 15);
        av2[mi] = aload16(&Zn[(size_t)bi * 1024 + 512 + ko]);
      }
      bv2 = *(const s16x8*)&WHMB[(size_t)(ns + (l & 15)) * 512 + ko];
#pragma unroll
      for (int mi = 0; mi < 2; mi++)
        m2[mi] = __builtin_amdgcn_mfma_f32_16x16x32_bf16(av2[mi], bv2, m2[mi], 0, 0, 0);
    }
    {
      float (*red2)[32][16] = (float(*)[32][16])SM;
#pragma unroll
      for (int mi = 0; mi < 2; mi++)
#pragma unroll
        for (int r = 0; r < 4; r++)
          red2[w][mi * 16 + (l >> 4) * 4 + r][l & 15] = m2[mi][r];
      __syncthreads();
      int bi = tid >> 3, j = (tid & 7) * 2;
      float v0 = red2[0][bi][j] + red2[1][bi][j] + red2[2][bi][j] + red2[3][bi][j];
      float v1 = red2[0][bi][j+1] + red2[1][bi][j+1] + red2[2][bi][j+1] + red2[3][bi][j+1];
      union { u64 q; float f[2]; } uu; uu.f[0] = v0; uu.f[1] = v1;
      __hip_atomic_store((u64*)(MAPPED + bi * 512 + ns + j), uu.q, __ATOMIC_RELAXED, SCOPE_AGENT);
    }
    bump_rel(&SYNC[SY_MF]);
  }
}

// ---------------- attention role (gid>=32): 32b x 7ch of 112 rows; combiner does out ----------------

static __device__ void attn_loop(const u16* __restrict__ CNNB, const u16* __restrict__ WOUT,
                                 const float* __restrict__ MAPPED,
                                 u16* __restrict__ Z, float* __restrict__ UB,
                                 float* __restrict__ MZb, u16* __restrict__ OALL,
                                 u32* __restrict__ SYNC, float* __restrict__ SM,
                                 u32* __restrict__ smu, int gid){
  int tid = threadIdx.x, w = tid >> 6, ln = tid & 63;
  int b = (gid - 32) & 31, ch = (gid - 32) >> 5;
  int l0 = ch * 112;
  float* sc   = SM;          // [112]
  float* sred = SM + 112;    // [4]
  float* accw = SM + 128;    // [4*512]
  float* cs   = SM + 2176;   // [512]
  float* hs   = SM + 2688;   // [512]
  float* mzs  = SM + 3200;   // [14]

  // V-rows pinned in registers for the whole decode (addresses step-invariant)
  s16x8 rowv[28];
  const u16* base = CNNB + ((size_t)(b * 784 + l0)) * 512 + ln * 8;
#pragma unroll
  for (int i = 0; i < 28; i++)
    rowv[i] = *(const s16x8*)(base + (size_t)(w + 4 * i) * 512);

  for (int t = 0; t < 256; ++t){
    flag_wait(&SYNC[SY_MF], 32u * (u32)(t + 1));
    float mp[8];
    {
      const u64* mq = (const u64*)(MAPPED + b * 512 + ln * 8);
#pragma unroll
      for (int j = 0; j < 4; j++){
        union { u64 q; float f[2]; } a;
        a.q = __hip_atomic_load(mq + j, __ATOMIC_RELAXED, SCOPE_AGENT);
        mp[2*j] = a.f[0]; mp[2*j+1] = a.f[1];
      }
    }
    // pass 1: scores
    float wmax = -1e30f;
#pragma unroll
    for (int i = 0; i < 28; i++){
      float d = 0.f;
#pragma unroll
      for (int j = 0; j < 8; j++) d = fmaf(mp[j], bf2f((u16)rowv[i][j]), d);
#pragma unroll
      for (int m = 1; m < 64; m <<= 1) d += __shfl_xor(d, m, 64);
      if (ln == 0) sc[w + 4 * i] = d;
      wmax = fmaxf(wmax, d);
    }
    if (ln == 0) sred[w] = wmax;
    __syncthreads();
    float M = fmaxf(fmaxf(sred[0], sred[1]), fmaxf(sred[2], sred[3]));
    __syncthreads();
    float s = 0.f;
    if (tid < 112){ float p = __expf(sc[tid] - M); sc[tid] = p; s = p; }
#pragma unroll
    for (int m = 1; m < 64; m <<= 1) s += __shfl_xor(s, m, 64);
    if (ln == 0) sred[w] = s;
    __syncthreads();
    float S = sred[0] + sred[1] + sred[2] + sred[3];
    // pass 2: weighted V from registers
    float a8[8] = {0.f,0.f,0.f,0.f,0.f,0.f,0.f,0.f};
#pragma unroll
    for (int i = 0; i < 28; i++){
      float p = sc[w + 4 * i];
#pragma unroll
      for (int j = 0; j < 8; j++) a8[j] = fmaf(p, bf2f((u16)rowv[i][j]), a8[j]);
    }
    {
      f32x4 x0 = {a8[0], a8[1], a8[2], a8[3]};
      f32x4 x1 = {a8[4], a8[5], a8[6], a8[7]};
      *(f32x4*)&accw[w * 512 + ln * 8]     = x0;
      *(f32x4*)&accw[w * 512 + ln * 8 + 4] = x1;
    }
    __syncthreads();
    int e0 = 2 * tid;
    {
      float u0 = accw[e0] + accw[512 + e0] + accw[1024 + e0] + accw[1536 + e0];
      float u1 = accw[e0+1] + accw[512 + e0+1] + accw[1024 + e0+1] + accw[1536 + e0+1];
      union { u64 q; float f[2]; } uu; uu.f[0] = u0; uu.f[1] = u1;
      __hip_atomic_store((u64*)(UB + ((size_t)(b * 7 + ch) * 512 + e0)), uu.q,
                         __ATOMIC_RELAXED, SCOPE_AGENT);
      if (tid == 0){
        union { u64 q; float f[2]; } mm; mm.f[0] = M; mm.f[1] = S;
        __hip_atomic_store((u64*)(MZb + (b * 7 + ch) * 2), mm.q, __ATOMIC_RELAXED, SCOPE_AGENT);
      }
    }
    asm volatile("s_waitcnt vmcnt(0)" ::: "memory");
    __syncthreads();
    if (tid == 0)
      smu[0] = __hip_atomic_fetch_add(&SYNC[SY_RDY + b], 1u, __ATOMIC_RELEASE, SCOPE_AGENT);
    __syncthreads();
    if (smu[0] % 7u == 6u){
      // ---- combiner: softmax-combine ctx -> out(b) ----
      u16* Zpar = Z + (t & 1) * 32768;
      if (tid < 7){
        union { u64 q; float f[2]; } a;
        a.q = __hip_atomic_load((const u64*)(MZb + (b * 7 + tid) * 2), __ATOMIC_RELAXED, SCOPE_AGENT);
        mzs[2 * tid] = a.f[0]; mzs[2 * tid + 1] = a.f[1];
      }
      __syncthreads();
      float Mg = -1e30f;
#pragma unroll
      for (int c = 0; c < 7; c++) Mg = fmaxf(Mg, mzs[2 * c]);
      float bet[7]; float Sg = 0.f;
#pragma unroll
      for (int c = 0; c < 7; c++){
        float e = __expf(mzs[2 * c] - Mg);
        bet[c] = e; Sg += e * mzs[2 * c + 1];
      }
      float inv = 1.f / Sg;
#pragma unroll
      for (int c = 0; c < 7; c++) bet[c] *= inv;
      float c0 = 0.f, c1 = 0.f;
#pragma unroll
      for (int c = 0; c < 7; c++){
        union { u64 q; float f[2]; } a;
        a.q = __hip_atomic_load((const u64*)(UB + ((size_t)(b * 7 + c) * 512 + e0)),
                                __ATOMIC_RELAXED, SCOPE_AGENT);
        c0 = fmaf(bet[c], a.f[0], c0); c1 = fmaf(bet[c], a.f[1], c1);
      }
      cs[e0] = c0; cs[e0 + 1] = c1;
      {
        u32 hv = __hip_atomic_load((const u32*)(Zpar + b * 1024 + 512 + e0),
                                   __ATOMIC_RELAXED, SCOPE_AGENT);
        hs[e0] = bf2f((u16)(hv & 0xffff)); hs[e0 + 1] = bf2f((u16)(hv >> 16));
      }
      __syncthreads();
      // out(b) cols [2*tid, 2*tid+1]
      int oc0 = e0;
      const u64* wr0 = (const u64*)(WOUT + (size_t)oc0 * 1024);
      const u64* wr1 = (const u64*)(WOUT + (size_t)(oc0 + 1) * 1024);
      float o0 = 0.f, o1 = 0.f;
      for (int kk = 0; kk < 128; kk++){
        u64 q0 = wr0[kk], q1 = wr1[kk];
#pragma unroll
        for (int j = 0; j < 4; j++){
          float f = cs[kk * 4 + j];
          o0 = fmaf(f, bf2f((u16)(q0 >> (16 * j))), o0);
          o1 = fmaf(f, bf2f((u16)(q1 >> (16 * j))), o1);
        }
      }
      for (int kk = 128; kk < 256; kk++){
        u64 q0 = wr0[kk], q1 = wr1[kk];
#pragma unroll
        for (int j = 0; j < 4; j++){
          float f = hs[kk * 4 - 512 + j];
          o0 = fmaf(f, bf2f((u16)(q0 >> (16 * j))), o0);
          o1 = fmaf(f, bf2f((u16)(q1 >> (16 * j))), o1);
        }
      }
      o0 = tanhf(o0); o1 = tanhf(o1);
      u32 pk = (u32)f2bf(o0) | ((u32)f2bf(o1) << 16);
      __hip_atomic_store((u32*)(Zpar + b * 1024 + oc0), pk, __ATOMIC_RELAXED, SCOPE_AGENT);
      *(u32*)&OALL[((size_t)(b * 256 + t)) * 512 + oc0] = pk;
      bump_rel(&SYNC[SY_OF]);
    }
  }
}

// ---------------- persistent decoder ----------------

__global__ __launch_bounds__(256, 1) void k_persist(const u16* __restrict__ WF,
                                                    const u16* __restrict__ XS,
                                                    const u16* __restrict__ CNNB,
                                                    const u16* __restrict__ WHMB,
                                                    const u16* __restrict__ WOUT,
                                                    u16* __restrict__ Z,
                                                    float* __restrict__ CST,
                                                    float* __restrict__ UB,
                                                    float* __restrict__ MZb,
                                                    float* __restrict__ MAPPED,
                                                    u16* __restrict__ OALL,
                                                    u32* __restrict__ SYNC){
  __shared__ __align__(16) float SM[8192];
  __shared__ u32 smu[1];
  int gid = blockIdx.x;
  if (gid < 32)
    gates_loop(WF, XS, WHMB, Z, CST, MAPPED, SYNC, SM, gid);
  else
    attn_loop(CNNB, WOUT, MAPPED, Z, UB, MZb, OALL, SYNC, SM, smu, gid);
}

// ---------------- log_softmax ----------------

__global__ __launch_bounds__(256) void k_lsm(float* __restrict__ x){
  size_t base = (size_t)blockIdx.x * 8000;
  int tid = threadIdx.x, w = tid >> 6, ln = tid & 63;
  __shared__ float sred[4];
  float m = -1e30f;
  for (int v = tid; v < 8000; v += 256) m = fmaxf(m, x[base + v]);
#pragma unroll
  for (int mk = 1; mk < 64; mk <<= 1) m = fmaxf(m, __shfl_xor(m, mk, 64));
  if (ln == 0) sred[w] = m;
  __syncthreads();
  float M = fmaxf(fmaxf(sred[0], sred[1]), fmaxf(sred[2], sred[3]));
  __syncthreads();
  float s = 0.f;
  for (int v = tid; v < 8000; v += 256) s += __expf(x[base + v] - M);
#pragma unroll
  for (int mk = 1; mk < 64; mk <<= 1) s += __shfl_xor(s, mk, 64);
  if (ln == 0) sred[w] = s;
  __syncthreads();
  float S = sred[0] + sred[1] + sred[2] + sred[3];
  float lz = M + logf(S);
  for (int v = tid; v < 8000; v += 256) x[base + v] -= lz;
}

// ---------------- launcher ----------------

extern "C" void kernel_launch(void* const* d_in, const int* in_sizes, int n_in,
                              void* d_out, int out_size, void* d_ws, size_t ws_size,
                              hipStream_t stream){
  const float* cnn  = (const float*)d_in[0];
  const int*   seq  = (const int*)d_in[1];
  const float* emb  = (const float*)d_in[2];
  const float* wih  = (const float*)d_in[3];
  const float* whh  = (const float*)d_in[4];
  const float* whm  = (const float*)d_in[5];
  const float* wo   = (const float*)d_in[6];
  const float* wlg  = (const float*)d_in[7];
  const float* blg  = (const float*)d_in[8];

  char* ws = (char*)d_ws;
  u16*   WF     = (u16*)(ws + 0);          // 2048x1280 bf16 = 5,242,880
  u16*   WHMB   = (u16*)(ws + 5242880);    // 512x512 bf16   =   524,288
  u16*   WOUT   = (u16*)(ws + 5767168);    // 512x1024 bf16  = 1,048,576
  u16*   WLOGIT = (u16*)(ws + 6815744);    // 8000x512 bf16  = 8,192,000
  u16*   CNNBF  = (u16*)(ws + 15007744);   // 25088x512 bf16 = 25,690,112
  u16*   XS     = (u16*)(ws + 40697856);   // [256][32][256] bf16 = 4,194,304
  u16*   OALL   = (u16*)(ws + 44892160);   // 8192x512 bf16  = 8,388,608
  u16*   Z      = (u16*)(ws + 53280768);   // [2][32][1024] bf16 = 131,072
  float* CST    = (float*)(ws + 53411840); // 32x512 f32     = 65,536
  float* UB     = (float*)(ws + 53477376); // [32][7][512] f32 = 458,752
  float* MZb    = (float*)(ws + 53936128); // [32][7][2] f32 = 1,792 (pad 2,048)
  float* MAPPED = (float*)(ws + 53938176); // [32][512] f32  = 65,536
  u32*   SYNC   = (u32*)(ws + 54003712);   // 4 KiB

  float* OUT = (float*)d_out;

  hipMemsetAsync(SYNC, 0, 4096, stream);
  k_wfull<<<512, 256, 0, stream>>>(wih, whh, WF);
  k_cvt<<<128, 256, 0, stream>>>(whm, WHMB, 512 * 512);
  k_cvt<<<512, 256, 0, stream>>>(wo, WOUT, 512 * 1024);
  k_cvt<<<2048, 256, 0, stream>>>(wlg, WLOGIT, 8000 * 512);
  k_cvt<<<2048, 256, 0, stream>>>(cnn, CNNBF, 25088 * 512);
  k_xs<<<2048, 256, 0, stream>>>(seq, emb, XS);

  k_persist<<<256, 256, 0, stream>>>(WF, XS, CNNBF, WHMB, WOUT, Z, CST, UB, MZb, MAPPED, OALL, SYNC);

  {
    dim3 g(64, 63);
    k_gemm<0, 1, 1><<<g, 256, 0, stream>>>(OALL, WLOGIT, OUT, blg, 8192, 8000, 512);
  }
  k_lsm<<<8192, 256, 0, stream>>>(OUT);
}

// Round 6
// 7248.164 us; speedup vs baseline: 2.7357x; 1.9957x over previous
//
#include <hip/hip_runtime.h>
#include <hip/hip_bf16.h>
#include <stdint.h>

typedef unsigned short u16;
typedef unsigned int u32;
typedef unsigned long long u64;
typedef __attribute__((ext_vector_type(8))) short s16x8;
typedef __attribute__((ext_vector_type(4))) float f32x4;

#define AGT __HIP_MEMORY_SCOPE_AGENT

static __device__ __forceinline__ float bf2f(u16 u){
  unsigned v = ((unsigned)u) << 16; return __builtin_bit_cast(float, v);
}
static __device__ __forceinline__ u16 f2bf(float f){
  unsigned u = __builtin_bit_cast(unsigned, f);
  u += 0x7FFFu + ((u >> 16) & 1u);
  return (u16)(u >> 16);
}
static __device__ __forceinline__ float sigm(float x){ return 1.f / (1.f + __expf(-x)); }

typedef __attribute__((address_space(1))) const u32 gu32;
typedef __attribute__((address_space(3))) u32 lu32;
static __device__ __forceinline__ void gload_lds16(const void* g, void* l){
  __builtin_amdgcn_global_load_lds((gu32*)g, (lu32*)l, 16, 0, 0);
}

// coherent 16B load via two 8B agent-scope atomic loads (LLC-fresh)
static __device__ __forceinline__ s16x8 aload16(const u16* p){
  union { u64 q[2]; s16x8 v; } u;
  u.q[0] = __hip_atomic_load((const u64*)p,     __ATOMIC_RELAXED, AGT);
  u.q[1] = __hip_atomic_load(((const u64*)p)+1, __ATOMIC_RELAXED, AGT);
  return u.v;
}

// SYNC layout (u32 idx; 32 u32 = one 128B line each)
#define SY_HG        0
#define SY_OG        32
#define SY_RDY(b)    (64 + (b)*32)
#define SY_OD(b)     (1088 + (b)*32)
#define SY_HPRIV(w)  (2112 + (w)*32)
#define SY_OPRIV(g)  (10304 + (g)*32)
#define SY_TOTAL_U32 11328

static __device__ __forceinline__ void drain(){
  asm volatile("s_waitcnt vmcnt(0)" ::: "memory");
}
// poll a PRIVATE line with fetch_add(0): always LLC-fresh, zero contention
static __device__ __forceinline__ void await_ge(u32* f, u32 target){
  if (threadIdx.x == 0){
    while (__hip_atomic_fetch_add(f, 0u, __ATOMIC_RELAXED, AGT) < target)
      __builtin_amdgcn_s_sleep(1);
  }
  __syncthreads();
}

// ---------------- prep kernels ----------------

__global__ __launch_bounds__(256) void k_wfull(const float* __restrict__ wih,
                                               const float* __restrict__ whh,
                                               u16* __restrict__ wf){
  int stride = gridDim.x * blockDim.x;
  for (int i = blockIdx.x * blockDim.x + threadIdx.x; i < 2048 * 1280; i += stride){
    int j = i / 1280, k = i - j * 1280;
    float v = (k < 768) ? wih[j * 768 + k] : whh[j * 512 + (k - 768)];
    wf[i] = f2bf(v);
  }
}

__global__ __launch_bounds__(256) void k_whmt(const float* __restrict__ whm,
                                              u16* __restrict__ wt){
  int stride = gridDim.x * blockDim.x;
  for (int i = blockIdx.x * blockDim.x + threadIdx.x; i < 512 * 512; i += stride){
    int n = i >> 9, k = i & 511;
    wt[i] = f2bf(whm[k * 512 + n]);     // WHMT[a][b] = whm[b][a]
  }
}

__global__ __launch_bounds__(256) void k_cvt(const float* __restrict__ s,
                                             u16* __restrict__ d, int n){
  int stride = gridDim.x * blockDim.x * 4;
  for (int i = (blockIdx.x * blockDim.x + threadIdx.x) * 4; i < n; i += stride){
    float4 v = *(const float4*)&s[i];
    d[i + 0] = f2bf(v.x); d[i + 1] = f2bf(v.y);
    d[i + 2] = f2bf(v.z); d[i + 3] = f2bf(v.w);
  }
}

// xs stored [t][b][e]
__global__ __launch_bounds__(256) void k_xs(const int* __restrict__ seq,
                                            const float* __restrict__ emb,
                                            u16* __restrict__ xs){
  int stride = gridDim.x * blockDim.x;
  for (int i = blockIdx.x * blockDim.x + threadIdx.x; i < 8192 * 256; i += stride){
    int m = i >> 8, e = i & 255;          // m = b*256 + t
    int b = m >> 8, t = m & 255;
    float v = emb[(size_t)seq[m] * 256 + e];
    xs[(size_t)(t * 32 + b) * 256 + e] = f2bf(v > 0.f ? v : 0.f);
  }
}

// ---------------- 128x128 bf16 MFMA GEMM: C = A[M,K] @ B[N,K]^T ----------------

template<int OUTBF, int HASBIAS, int NG>
__global__ __launch_bounds__(256) void k_gemm(const u16* __restrict__ A,
                                              const u16* __restrict__ Bm,
                                              void* __restrict__ Cout,
                                              const float* __restrict__ bias,
                                              int M, int N, int K){
  __shared__ __align__(16) u16 As[128 * 64];
  __shared__ __align__(16) u16 Bs[128 * 64];
  int tid = threadIdx.x; int w = tid >> 6; int l = tid & 63;
  int m0 = blockIdx.x * 128, n0 = blockIdx.y * 128;
  int wr = w >> 1, wc = w & 1;
  f32x4 acc[4][4];
#pragma unroll
  for (int a = 0; a < 4; a++)
#pragma unroll
    for (int b = 0; b < 4; b++){ f32x4 z = {0.f,0.f,0.f,0.f}; acc[a][b] = z; }
  int rA = m0 + (tid >> 3);
  int rB = n0 + (tid >> 3);
  for (int k0 = 0; k0 < K; k0 += 64){
    __syncthreads();
    int ca = k0 + (tid & 7) * 8;
#pragma unroll
    for (int i = 0; i < 4; i++){
      gload_lds16(&A[(size_t)(rA + i * 32) * K + ca], &As[i * 2048 + w * 512]);
      int rb = rB + i * 32;
      if (NG) rb = (rb < N - 1) ? rb : (N - 1);
      gload_lds16(&Bm[(size_t)rb * K + ca], &Bs[i * 2048 + w * 512]);
    }
    asm volatile("s_waitcnt vmcnt(0)" ::: "memory");
    __syncthreads();
#pragma unroll
    for (int ks = 0; ks < 2; ks++){
      s16x8 av[4], bv[4];
      int ko = ks * 32 + (l >> 4) * 8;
#pragma unroll
      for (int i = 0; i < 4; i++) av[i] = *(const s16x8*)&As[(wr * 64 + i * 16 + (l & 15)) * 64 + ko];
#pragma unroll
      for (int i = 0; i < 4; i++) bv[i] = *(const s16x8*)&Bs[(wc * 64 + i * 16 + (l & 15)) * 64 + ko];
#pragma unroll
      for (int mi = 0; mi < 4; mi++)
#pragma unroll
        for (int ni = 0; ni < 4; ni++)
          acc[mi][ni] = __builtin_amdgcn_mfma_f32_16x16x32_bf16(av[mi], bv[ni], acc[mi][ni], 0, 0, 0);
    }
  }
#pragma unroll
  for (int mi = 0; mi < 4; mi++)
#pragma unroll
    for (int ni = 0; ni < 4; ni++){
      int row = m0 + wr * 64 + mi * 16 + (l >> 4) * 4;
      int col = n0 + wc * 64 + ni * 16 + (l & 15);
      if (NG && col >= N) continue;
#pragma unroll
      for (int r = 0; r < 4; r++){
        float v = acc[mi][ni][r];
        if (HASBIAS) v += bias[col];
        if (OUTBF) ((u16*)Cout)[(size_t)(row + r) * N + col] = f2bf(v);
        else       ((float*)Cout)[(size_t)(row + r) * N + col] = v;
      }
    }
}

// ---------------- gates role (gid<32): W pinned in VGPRs ----------------

static __device__ void gates_role(const u16* __restrict__ WF, const u16* __restrict__ XS,
                                  u16* __restrict__ Z, float* __restrict__ CST,
                                  u32* __restrict__ SYNC, float* __restrict__ SM,
                                  u32* __restrict__ smu, int g){
  const int tid = threadIdx.x, w = tid >> 6, l = tid & 63;
  const int ns = g << 4;
  float (*red)[32][64] = (float(*)[32][64])SM;

  // pin step-invariant W slices in registers: x(8) + h(16) + out(16) s16x8 = 160 VGPR
  s16x8 bx[2][4], bh[4][4], bo[4][4];
#pragma unroll
  for (int ki = 0; ki < 2; ki++){
    int ko = w * 64 + ki * 32 + (l >> 4) * 8;
#pragma unroll
    for (int gi = 0; gi < 4; gi++)
      bx[ki][gi] = *(const s16x8*)&WF[(size_t)(gi * 512 + ns + (l & 15)) * 1280 + ko];
  }
#pragma unroll
  for (int ki = 0; ki < 4; ki++){
    int koh = 768 + w * 128 + ki * 32 + (l >> 4) * 8;
    int koo = 256 + w * 128 + ki * 32 + (l >> 4) * 8;
#pragma unroll
    for (int gi = 0; gi < 4; gi++){
      bh[ki][gi] = *(const s16x8*)&WF[(size_t)(gi * 512 + ns + (l & 15)) * 1280 + koh];
      bo[ki][gi] = *(const s16x8*)&WF[(size_t)(gi * 512 + ns + (l & 15)) * 1280 + koo];
    }
  }
  u32* hpriv = &SYNC[SY_HPRIV(g)];
  u32* opriv = &SYNC[SY_OPRIV(g)];

  for (int t = 0; t < 256; ++t){
    u16* Zn = Z + (t & 1) * 32768;
    const u16* Zp = Z + ((t + 1) & 1) * 32768;
    f32x4 acc[2][4];
#pragma unroll
    for (int a = 0; a < 2; a++)
#pragma unroll
      for (int b = 0; b < 4; b++){ f32x4 z = {0.f,0.f,0.f,0.f}; acc[a][b] = z; }

    // x segment (no dependency)
#pragma unroll
    for (int ki = 0; ki < 2; ki++){
      int ko = w * 64 + ki * 32 + (l >> 4) * 8;
      s16x8 av[2];
#pragma unroll
      for (int mi = 0; mi < 2; mi++)
        av[mi] = *(const s16x8*)&XS[(size_t)(t * 32 + mi * 16 + (l & 15)) * 256 + ko];
#pragma unroll
      for (int mi = 0; mi < 2; mi++)
#pragma unroll
        for (int gi = 0; gi < 4; gi++)
          acc[mi][gi] = __builtin_amdgcn_mfma_f32_16x16x32_bf16(av[mi], bx[ki][gi], acc[mi][gi], 0, 0, 0);
    }
    if (t > 0){
      await_ge(hpriv, (u32)t);                 // h(t-1) complete
#pragma unroll
      for (int ki = 0; ki < 4; ki++){
        int ko = 768 + w * 128 + ki * 32 + (l >> 4) * 8;
        s16x8 av[2];
#pragma unroll
        for (int mi = 0; mi < 2; mi++)
          av[mi] = aload16(&Zp[(size_t)(mi * 16 + (l & 15)) * 1024 + (ko - 256)]);
#pragma unroll
        for (int mi = 0; mi < 2; mi++)
#pragma unroll
          for (int gi = 0; gi < 4; gi++)
            acc[mi][gi] = __builtin_amdgcn_mfma_f32_16x16x32_bf16(av[mi], bh[ki][gi], acc[mi][gi], 0, 0, 0);
      }
      await_ge(opriv, (u32)t);                 // out(t-1) complete
#pragma unroll
      for (int ki = 0; ki < 4; ki++){
        int ko = 256 + w * 128 + ki * 32 + (l >> 4) * 8;
        s16x8 av[2];
#pragma unroll
        for (int mi = 0; mi < 2; mi++)
          av[mi] = aload16(&Zp[(size_t)(mi * 16 + (l & 15)) * 1024 + (ko - 256)]);
#pragma unroll
        for (int mi = 0; mi < 2; mi++)
#pragma unroll
          for (int gi = 0; gi < 4; gi++)
            acc[mi][gi] = __builtin_amdgcn_mfma_f32_16x16x32_bf16(av[mi], bo[ki][gi], acc[mi][gi], 0, 0, 0);
      }
    }
    // cross-wave reduce + LSTM
#pragma unroll
    for (int mi = 0; mi < 2; mi++)
#pragma unroll
      for (int gi = 0; gi < 4; gi++)
#pragma unroll
        for (int r = 0; r < 4; r++)
          red[w][mi * 16 + (l >> 4) * 4 + r][gi * 16 + (l & 15)] = acc[mi][gi][r];
    __syncthreads();
    {
      int bi = tid >> 3, j = (tid & 7) * 2;
      float iv0=0,fv0=0,gv0=0,ov0=0, iv1=0,fv1=0,gv1=0,ov1=0;
#pragma unroll
      for (int qq = 0; qq < 4; qq++){
        iv0 += red[qq][bi][j];      fv0 += red[qq][bi][16 + j];
        gv0 += red[qq][bi][32 + j]; ov0 += red[qq][bi][48 + j];
        iv1 += red[qq][bi][j + 1];      fv1 += red[qq][bi][16 + j + 1];
        gv1 += red[qq][bi][32 + j + 1]; ov1 += red[qq][bi][48 + j + 1];
      }
      int n0 = ns + j;
      float c0 = (t > 0) ? CST[bi * 512 + n0]     : 0.f;
      float c1 = (t > 0) ? CST[bi * 512 + n0 + 1] : 0.f;
      float cn0 = sigm(fv0) * c0 + sigm(iv0) * tanhf(gv0);
      float cn1 = sigm(fv1) * c1 + sigm(iv1) * tanhf(gv1);
      float h0 = sigm(ov0) * tanhf(cn0);
      float h1 = sigm(ov1) * tanhf(cn1);
      CST[bi * 512 + n0] = cn0; CST[bi * 512 + n0 + 1] = cn1;
      u32 pk = (u32)f2bf(h0) | ((u32)f2bf(h1) << 16);
      __hip_atomic_store((u32*)(Zn + bi * 1024 + 512 + n0), pk, __ATOMIC_RELAXED, AGT);
    }
    drain();
    __syncthreads();
    if (tid == 0)
      smu[0] = __hip_atomic_fetch_add(&SYNC[SY_HG], 1u, __ATOMIC_RELAXED, AGT);
    __syncthreads();
    if ((smu[0] & 31u) == 31u)   // 32nd bump of this step: fan out to all 256 consumers
      __hip_atomic_store(&SYNC[SY_HPRIV(tid)], (u32)(t + 1), __ATOMIC_RELAXED, AGT);
  }
}

// ---------------- attn+out role (gid>=32): V and CNN2 rows pinned in VGPRs ----------------

static __device__ void attn_role(const u16* __restrict__ CNN2, const u16* __restrict__ CNNB,
                                 const u16* __restrict__ WOUT, u16* __restrict__ Z,
                                 float* __restrict__ UPART, float* __restrict__ MS,
                                 u16* __restrict__ OALL, u32* __restrict__ SYNC,
                                 float* __restrict__ SM, u32* __restrict__ smu, int q){
  const int tid = threadIdx.x, w = tid >> 6, ln = tid & 63;
  const int b = q / 7, ch = q - b * 7;
  const int l0 = ch * 112;
  const int nc = (ch == 6) ? 68 : 74, cs = ch * 74;
  float* sc   = SM;          // [112]
  float* sred = SM + 112;    // [4]
  float* msh  = SM + 120;    // [14]
  float* csf  = SM + 144;    // [512]
  float* hsf  = SM + 656;    // [512]
  float* accw = SM + 1184;   // [4*512]
  float* ored = SM + 3232;   // [160]

  // pin V rows and CNN2 rows (step-invariant) : 56 s16x8 = 224 VGPR
  s16x8 rowv[28], c2v[28];
  {
    const u16* vb = CNNB + ((size_t)(b * 784 + l0)) * 512 + ln * 8;
    const u16* cb = CNN2 + ((size_t)(b * 784 + l0)) * 512 + ln * 8;
#pragma unroll
    for (int i = 0; i < 28; i++){
      rowv[i] = *(const s16x8*)(vb + (size_t)(w + 4 * i) * 512);
      c2v[i]  = *(const s16x8*)(cb + (size_t)(w + 4 * i) * 512);
    }
  }
  u32* hpriv = &SYNC[SY_HPRIV(32 + q)];
  u32* rdy   = &SYNC[SY_RDY(b)];

  for (int t = 0; t < 256; ++t){
    await_ge(hpriv, (u32)(t + 1));           // h(t) complete
    u16* Zpar = Z + (t & 1) * 32768;
    float mp[8];
    {
      s16x8 hv = aload16(Zpar + b * 1024 + 512 + ln * 8);
#pragma unroll
      for (int j = 0; j < 8; j++) mp[j] = bf2f((u16)hv[j]);
    }
    // scores from pinned CNN2 rows: s_l = cnn2_l . h
    float wmax = -1e30f;
#pragma unroll
    for (int i = 0; i < 28; i++){
      float d = 0.f;
#pragma unroll
      for (int j = 0; j < 8; j++) d = fmaf(mp[j], bf2f((u16)c2v[i][j]), d);
#pragma unroll
      for (int m = 1; m < 64; m <<= 1) d += __shfl_xor(d, m, 64);
      if (ln == 0) sc[w + 4 * i] = d;
      wmax = fmaxf(wmax, d);
    }
    if (ln == 0) sred[w] = wmax;
    __syncthreads();
    float M = fmaxf(fmaxf(sred[0], sred[1]), fmaxf(sred[2], sred[3]));
    __syncthreads();
    float s = 0.f;
    if (tid < 112){ float p = __expf(sc[tid] - M); sc[tid] = p; s = p; }
#pragma unroll
    for (int m = 1; m < 64; m <<= 1) s += __shfl_xor(s, m, 64);
    if (ln == 0) sred[w] = s;
    __syncthreads();
    float S = sred[0] + sred[1] + sred[2] + sred[3];
    // weighted V from pinned registers
    float a8[8] = {0.f,0.f,0.f,0.f,0.f,0.f,0.f,0.f};
#pragma unroll
    for (int i = 0; i < 28; i++){
      float p = sc[w + 4 * i];
#pragma unroll
      for (int j = 0; j < 8; j++) a8[j] = fmaf(p, bf2f((u16)rowv[i][j]), a8[j]);
    }
    {
      f32x4 x0 = {a8[0], a8[1], a8[2], a8[3]};
      f32x4 x1 = {a8[4], a8[5], a8[6], a8[7]};
      *(f32x4*)&accw[w * 512 + ln * 8]     = x0;
      *(f32x4*)&accw[w * 512 + ln * 8 + 4] = x1;
    }
    __syncthreads();
    int e0 = 2 * tid;
    {
      float u0 = accw[e0] + accw[512 + e0] + accw[1024 + e0] + accw[1536 + e0];
      float u1 = accw[e0+1] + accw[512 + e0+1] + accw[1024 + e0+1] + accw[1536 + e0+1];
      union { u64 qv; float f[2]; } uu; uu.f[0] = u0; uu.f[1] = u1;
      __hip_atomic_store((u64*)(UPART + ((size_t)(b * 7 + ch) * 512 + e0)), uu.qv,
                         __ATOMIC_RELAXED, AGT);
      if (tid == 0){
        union { u64 qv; float f[2]; } mm; mm.f[0] = M; mm.f[1] = S;
        __hip_atomic_store((u64*)(MS + (b * 7 + ch) * 2), mm.qv, __ATOMIC_RELAXED, AGT);
      }
    }
    drain();
    __syncthreads();
    if (tid == 0)
      __hip_atomic_fetch_add(rdy, 1u, __ATOMIC_RELAXED, AGT);
    await_ge(rdy, 7u * (u32)(t + 1));        // all 7 partials of batch b
    // combine (every chunk wg does it locally; 14 KB reads)
    if (tid < 7){
      union { u64 qv; float f[2]; } a;
      a.qv = __hip_atomic_load((const u64*)(MS + (b * 7 + tid) * 2), __ATOMIC_RELAXED, AGT);
      msh[2 * tid] = a.f[0]; msh[2 * tid + 1] = a.f[1];
    }
    __syncthreads();
    float Mg = -1e30f;
#pragma unroll
    for (int c = 0; c < 7; c++) Mg = fmaxf(Mg, msh[2 * c]);
    float bet[7]; float Sg = 0.f;
#pragma unroll
    for (int c = 0; c < 7; c++){
      float e = __expf(msh[2 * c] - Mg);
      bet[c] = e; Sg += e * msh[2 * c + 1];
    }
    float inv = 1.f / Sg;
    {
      float c0 = 0.f, c1 = 0.f;
#pragma unroll
      for (int c = 0; c < 7; c++){
        union { u64 qv; float f[2]; } a;
        a.qv = __hip_atomic_load((const u64*)(UPART + ((size_t)(b * 7 + c) * 512 + e0)),
                                 __ATOMIC_RELAXED, AGT);
        float bc = bet[c] * inv;
        c0 = fmaf(bc, a.f[0], c0); c1 = fmaf(bc, a.f[1], c1);
      }
      csf[e0] = c0; csf[e0 + 1] = c1;
      u32 hv2 = __hip_atomic_load((const u32*)(Zpar + b * 1024 + 512 + e0),
                                  __ATOMIC_RELAXED, AGT);
      hsf[e0] = bf2f((u16)(hv2 & 0xffff)); hsf[e0 + 1] = bf2f((u16)(hv2 >> 16));
    }
    __syncthreads();
    // out slice: cols [cs, cs+nc), (col, K-half) per thread
    if (tid < 2 * nc){
      int col = cs + (tid >> 1), half = tid & 1;
      const s16x8* wr = (const s16x8*)(WOUT + (size_t)col * 1024 + half * 512);
      const float* src = half ? hsf : csf;
      float o = 0.f;
      for (int kk = 0; kk < 64; kk++){
        s16x8 qv = wr[kk];
#pragma unroll
        for (int j = 0; j < 8; j++) o = fmaf(src[kk * 8 + j], bf2f((u16)qv[j]), o);
      }
      ored[tid] = o;
    }
    __syncthreads();
    if (tid < (nc >> 1)){
      int q0 = 2 * tid, q1 = 2 * tid + 1;
      float v0 = tanhf(ored[2 * q0] + ored[2 * q0 + 1]);
      float v1 = tanhf(ored[2 * q1] + ored[2 * q1 + 1]);
      u32 pk = (u32)f2bf(v0) | ((u32)f2bf(v1) << 16);
      __hip_atomic_store((u32*)(Zpar + b * 1024 + cs + q0), pk, __ATOMIC_RELAXED, AGT);
      *(u32*)&OALL[((size_t)(b * 256 + t)) * 512 + cs + q0] = pk;
    }
    drain();
    __syncthreads();
    if (tid == 0)
      smu[0] = __hip_atomic_fetch_add(&SYNC[SY_OD(b)], 1u, __ATOMIC_RELAXED, AGT);
    __syncthreads();
    if (smu[0] % 7u == 6u){                  // 7th out-slice of batch b this step
      if (tid == 0)
        smu[1] = __hip_atomic_fetch_add(&SYNC[SY_OG], 1u, __ATOMIC_RELAXED, AGT);
      __syncthreads();
      if ((smu[1] & 31u) == 31u && tid < 32) // 32nd batch: fan out to 32 gate wgs
        __hip_atomic_store(&SYNC[SY_OPRIV(tid)], (u32)(t + 1), __ATOMIC_RELAXED, AGT);
    }
  }
}

// ---------------- persistent decoder ----------------

__global__ __launch_bounds__(256, 1) void k_persist(const u16* __restrict__ WF,
                                                    const u16* __restrict__ XS,
                                                    const u16* __restrict__ CNN2,
                                                    const u16* __restrict__ CNNB,
                                                    const u16* __restrict__ WOUT,
                                                    u16* __restrict__ Z,
                                                    float* __restrict__ CST,
                                                    float* __restrict__ UPART,
                                                    float* __restrict__ MS,
                                                    u16* __restrict__ OALL,
                                                    u32* __restrict__ SYNC){
  __shared__ __align__(16) float SM[8192];
  __shared__ u32 smu[2];
  int gid = blockIdx.x;
  if (gid < 32)
    gates_role(WF, XS, Z, CST, SYNC, SM, smu, gid);
  else
    attn_role(CNN2, CNNB, WOUT, Z, UPART, MS, OALL, SYNC, SM, smu, gid - 32);
}

// ---------------- log_softmax ----------------

__global__ __launch_bounds__(256) void k_lsm(float* __restrict__ x){
  size_t base = (size_t)blockIdx.x * 8000;
  int tid = threadIdx.x, w = tid >> 6, ln = tid & 63;
  __shared__ float sred[4];
  float m = -1e30f;
  for (int v = tid; v < 8000; v += 256) m = fmaxf(m, x[base + v]);
#pragma unroll
  for (int mk = 1; mk < 64; mk <<= 1) m = fmaxf(m, __shfl_xor(m, mk, 64));
  if (ln == 0) sred[w] = m;
  __syncthreads();
  float M = fmaxf(fmaxf(sred[0], sred[1]), fmaxf(sred[2], sred[3]));
  __syncthreads();
  float s = 0.f;
  for (int v = tid; v < 8000; v += 256) s += __expf(x[base + v] - M);
#pragma unroll
  for (int mk = 1; mk < 64; mk <<= 1) s += __shfl_xor(s, mk, 64);
  if (ln == 0) sred[w] = s;
  __syncthreads();
  float S = sred[0] + sred[1] + sred[2] + sred[3];
  float lz = M + logf(S);
  for (int v = tid; v < 8000; v += 256) x[base + v] -= lz;
}

// ---------------- launcher ----------------

extern "C" void kernel_launch(void* const* d_in, const int* in_sizes, int n_in,
                              void* d_out, int out_size, void* d_ws, size_t ws_size,
                              hipStream_t stream){
  const float* cnn  = (const float*)d_in[0];
  const int*   seq  = (const int*)d_in[1];
  const float* emb  = (const float*)d_in[2];
  const float* wih  = (const float*)d_in[3];
  const float* whh  = (const float*)d_in[4];
  const float* whm  = (const float*)d_in[5];
  const float* wo   = (const float*)d_in[6];
  const float* wlg  = (const float*)d_in[7];
  const float* blg  = (const float*)d_in[8];

  char* ws = (char*)d_ws;
  u16*   WF     = (u16*)(ws + 0);          // 2048x1280 bf16 = 5,242,880
  u16*   WHMT   = (u16*)(ws + 5242880);    // 512x512 bf16   =   524,288
  u16*   WOUT   = (u16*)(ws + 5767168);    // 512x1024 bf16  = 1,048,576
  u16*   WLOGIT = (u16*)(ws + 6815744);    // 8000x512 bf16  = 8,192,000
  u16*   CNNBF  = (u16*)(ws + 15007744);   // 25088x512 bf16 = 25,690,112
  u16*   CNN2   = (u16*)(ws + 40697856);   // 25088x512 bf16 = 25,690,112
  u16*   XS     = (u16*)(ws + 66387968);   // [256][32][256] bf16 = 4,194,304
  u16*   OALL   = (u16*)(ws + 70582272);   // 8192x512 bf16  = 8,388,608
  u16*   Z      = (u16*)(ws + 78970880);   // [2][32][1024] bf16 = 131,072
  float* CST    = (float*)(ws + 79101952); // 32x512 f32     = 65,536
  float* UPART  = (float*)(ws + 79167488); // [32][7][512] f32 = 458,752
  float* MS     = (float*)(ws + 79626240); // [32][7][2] f32 (pad 2048)
  u32*   SYNC   = (u32*)(ws + 79628288);   // 46,080 B -> ends 79,674,368

  float* OUT = (float*)d_out;

  hipMemsetAsync(SYNC, 0, 46080, stream);
  k_wfull<<<512, 256, 0, stream>>>(wih, whh, WF);
  k_whmt<<<128, 256, 0, stream>>>(whm, WHMT);
  k_cvt<<<512, 256, 0, stream>>>(wo, WOUT, 512 * 1024);
  k_cvt<<<2048, 256, 0, stream>>>(wlg, WLOGIT, 8000 * 512);
  k_cvt<<<2048, 256, 0, stream>>>(cnn, CNNBF, 25088 * 512);
  k_xs<<<2048, 256, 0, stream>>>(seq, emb, XS);

  {
    dim3 g(196, 4);   // CNN2 = CNNB @ WHMT^T : scores key matrix
    k_gemm<1, 0, 0><<<g, 256, 0, stream>>>(CNNBF, WHMT, CNN2, nullptr, 25088, 512, 512);
  }

  k_persist<<<256, 256, 0, stream>>>(WF, XS, CNN2, CNNBF, WOUT, Z, CST, UPART, MS, OALL, SYNC);

  {
    dim3 g(64, 63);
    k_gemm<0, 1, 1><<<g, 256, 0, stream>>>(OALL, WLOGIT, OUT, blg, 8192, 8000, 512);
  }
  k_lsm<<<8192, 256, 0, stream>>>(OUT);
}